// Round 12
// baseline (789.330 us; speedup 1.0000x reference)
//
#include <hip/hip_runtime.h>
#include <hip/hip_bf16.h>
#include <math.h>

typedef __attribute__((ext_vector_type(8))) __bf16 bf16x8;
typedef __attribute__((ext_vector_type(4))) float f32x4;
typedef __attribute__((ext_vector_type(4))) unsigned short u16x4;

#define HD  128
#define LDP 136

__device__ __forceinline__ unsigned short f2bf(float f) {
  __bf16 h = (__bf16)f;
  union { __bf16 h; unsigned short u; } v; v.h = h; return v.u;
}
__device__ __forceinline__ float bf2f(unsigned short h) {
  union { unsigned u; float f; } v; v.u = ((unsigned)h) << 16; return v.f;
}

__device__ __forceinline__ int idx_at(const void* p, long long i, int is64) {
  if (is64) return (int)((const long long*)p)[i];
  return ((const int*)p)[i];
}

// 128x128 += A(LDS bf16 LDP) @ B^T(LDS bf16 LDP). wave w: rows [w*32,w*32+32)
// D: m = w*32+mt*16+(lane>>4)*4+r, n = nt*16+(lane&15)
__device__ __forceinline__ void mfma_tile_128(const unsigned short* a_s,
                                              const unsigned short* w_s,
                                              int w, int l15, int lg,
                                              f32x4 acc[2][8]) {
#pragma unroll
  for (int kk = 0; kk < 4; ++kk) {
    bf16x8 a[2], b[8];
#pragma unroll
    for (int mt = 0; mt < 2; ++mt)
      a[mt] = *(const bf16x8*)&a_s[(w * 32 + mt * 16 + l15) * LDP + kk * 32 + lg * 8];
#pragma unroll
    for (int nt = 0; nt < 8; ++nt)
      b[nt] = *(const bf16x8*)&w_s[(nt * 16 + l15) * LDP + kk * 32 + lg * 8];
#pragma unroll
    for (int mt = 0; mt < 2; ++mt)
#pragma unroll
      for (int nt = 0; nt < 8; ++nt)
        acc[mt][nt] = __builtin_amdgcn_mfma_f32_16x16x32_bf16(a[mt], b[nt], acc[mt][nt], 0, 0, 0);
  }
}

// B fragments from GLOBAL bf16 [128][ldw] (L2-hot weights)
__device__ __forceinline__ void mfma_tile_gb(const unsigned short* a_s,
                                             const unsigned short* Wb, int ldw,
                                             int w, int l15, int lg,
                                             f32x4 acc[2][8]) {
#pragma unroll
  for (int kk = 0; kk < 4; ++kk) {
    bf16x8 a[2], b[8];
#pragma unroll
    for (int mt = 0; mt < 2; ++mt)
      a[mt] = *(const bf16x8*)&a_s[(w * 32 + mt * 16 + l15) * LDP + kk * 32 + lg * 8];
#pragma unroll
    for (int nt = 0; nt < 8; ++nt)
      b[nt] = *(const bf16x8*)&Wb[(size_t)(nt * 16 + l15) * ldw + kk * 32 + lg * 8];
#pragma unroll
    for (int mt = 0; mt < 2; ++mt)
#pragma unroll
      for (int nt = 0; nt < 8; ++nt)
        acc[mt][nt] = __builtin_amdgcn_mfma_f32_16x16x32_bf16(a[mt], b[nt], acc[mt][nt], 0, 0, 0);
  }
}

__device__ __forceinline__ void stage_f32s(unsigned short* dst, const float* src,
                                           long long src_ld, int tid, int T) {
  for (int i = tid; i < 128 * 32; i += T) {
    int r = i >> 5, c = (i & 31) << 2;
    float4 f = *(const float4*)&src[(long long)r * src_ld + c];
    u16x4 h = { f2bf(f.x), f2bf(f.y), f2bf(f.z), f2bf(f.w) };
    *(u16x4*)&dst[r * LDP + c] = h;
  }
}

// ---------------- index dtype detector ----------------
__global__ void detect_idx_kernel(const void* __restrict__ ei, int E, int N,
                                  int* __restrict__ flag) {
  if (threadIdx.x == 0 && blockIdx.x == 0) {
    const long long* p = (const long long*)ei;
    int is64 = 1;
    long long step = E / 64; if (step < 1) step = 1;
    for (int i = 0; i < 64; ++i) {
      long long v = p[i * step];
      if (v < 0 || v >= N) { is64 = 0; break; }
    }
    *flag = is64;
  }
}

// ---------------- f32 -> bf16 pre-converts ----------------
// We -> plain [128][128] bf16 (consumed via mfma_tile_gb from L2)
__global__ __launch_bounds__(256) void conv_we_kernel(const float* __restrict__ We,
                                                      unsigned short* __restrict__ we_bf) {
  int i = blockIdx.x * 256 + threadIdx.x;
  if (i < 128 * 128) we_bf[i] = f2bf(We[i]);
}
__global__ __launch_bounds__(256) void conv_weights_kernel(
    const float* __restrict__ W1, const float* __restrict__ W2,
    const float* __restrict__ inw, const float* __restrict__ wo,
    const float* __restrict__ f1, const float* __restrict__ f2,
    unsigned short* __restrict__ w1b, unsigned short* __restrict__ w2b,
    unsigned short* __restrict__ inwb, unsigned short* __restrict__ wob,
    unsigned short* __restrict__ f1b, unsigned short* __restrict__ f2b) {
  int i = blockIdx.x * 256 + threadIdx.x;
  if (i < 16384) w1b[i] = f2bf(W1[i]);
  else if (i < 32768) w2b[i - 16384] = f2bf(W2[i - 16384]);
  else if (i < 81920) inwb[i - 32768] = f2bf(inw[i - 32768]);
  else if (i < 98304) wob[i - 81920] = f2bf(wo[i - 81920]);
  else if (i < 131072) f1b[i - 98304] = f2bf(f1[i - 98304]);
  else if (i < 163840) f2b[i - 131072] = f2bf(f2[i - 131072]);
}
__global__ __launch_bounds__(256) void conv_x_kernel(const float* __restrict__ x,
                                                     unsigned short* __restrict__ xb,
                                                     long long n8) {
  long long i = blockIdx.x * 256LL + threadIdx.x;
  if (i < n8) {
    float4 f0 = *(const float4*)&x[i * 8];
    float4 f1 = *(const float4*)&x[i * 8 + 4];
    u16x4 h0 = { f2bf(f0.x), f2bf(f0.y), f2bf(f0.z), f2bf(f0.w) };
    u16x4 h1 = { f2bf(f1.x), f2bf(f1.y), f2bf(f1.z), f2bf(f1.w) };
    *(u16x4*)&xb[i * 8] = h0;
    *(u16x4*)&xb[i * 8 + 4] = h1;
  }
}

// ---------------- dst histogram ----------------
__global__ __launch_bounds__(256) void hist_kernel(const void* __restrict__ ei,
                                                   const int* __restrict__ flag,
                                                   int* __restrict__ deg, int E) {
  const int is64 = *flag;
  for (long long e = blockIdx.x * 256LL + threadIdx.x; e < E;
       e += (long long)gridDim.x * 256)
    atomicAdd(&deg[idx_at(ei, (long long)E + e, is64)], 1);
}

// ---------------- 3-phase exclusive scan ----------------
#define SCH 1024
__global__ __launch_bounds__(256) void scan_a(const int* __restrict__ deg,
                                              int* __restrict__ bsum, int N) {
  const int b = blockIdx.x, t = threadIdx.x;
  int p = 0;
#pragma unroll
  for (int k = 0; k < 4; ++k) {
    int idx = b * SCH + t * 4 + k;
    if (idx < N) p += deg[idx];
  }
  __shared__ int warr[4];
  for (int o = 32; o > 0; o >>= 1) p += __shfl_xor(p, o);
  if ((t & 63) == 0) warr[t >> 6] = p;
  __syncthreads();
  if (t == 0) bsum[b] = warr[0] + warr[1] + warr[2] + warr[3];
}
__global__ void scan_b(int* __restrict__ bsum, int* __restrict__ off, int NB, int N) {
  if (threadIdx.x == 0 && blockIdx.x == 0) {
    int run = 0;
    for (int b = 0; b < NB; ++b) { int t = bsum[b]; bsum[b] = run; run += t; }
    off[N] = run;
  }
}
__global__ __launch_bounds__(128) void scan_b2(int* __restrict__ bsum,
                                               int* __restrict__ off, int NB, int N) {
  __shared__ int arr[128];
  const int t = threadIdx.x;
  int v = (t < NB) ? bsum[t] : 0;
  arr[t] = v;
  __syncthreads();
  for (int s = 1; s < 128; s <<= 1) {
    int u = (t >= s) ? arr[t - s] : 0;
    __syncthreads();
    arr[t] += u;
    __syncthreads();
  }
  if (t < NB) bsum[t] = arr[t] - v;
  if (t == 0) off[N] = arr[127];
}
__global__ __launch_bounds__(256) void scan_c(const int* __restrict__ deg,
                                              const int* __restrict__ bsum,
                                              int* __restrict__ off,
                                              int* __restrict__ cursor, int N) {
  const int b = blockIdx.x, t = threadIdx.x;
  int d[4], s = 0;
#pragma unroll
  for (int k = 0; k < 4; ++k) {
    int idx = b * SCH + t * 4 + k;
    d[k] = (idx < N) ? deg[idx] : 0;
    s += d[k];
  }
  __shared__ int arr[256];
  arr[t] = s;
  __syncthreads();
  for (int stp = 1; stp < 256; stp <<= 1) {
    int v = (t >= stp) ? arr[t - stp] : 0;
    __syncthreads();
    arr[t] += v;
    __syncthreads();
  }
  int base = bsum[b] + arr[t] - s;
  int acc = 0;
#pragma unroll
  for (int k = 0; k < 4; ++k) {
    int idx = b * SCH + t * 4 + k;
    if (idx < N) { off[idx] = base + acc; cursor[idx] = base + acc; }
    acc += d[k];
  }
}

// -------- edge kernel v12: A->regs streaming, B(We) from L2 global, 1 barrier ------
__global__ __launch_bounds__(256, 4) void edge_kernel12(
    const unsigned short* __restrict__ x_bf, const float* __restrict__ ea,
    const unsigned short* __restrict__ we_bf, const float* __restrict__ be,
    const void* __restrict__ ei, const int* __restrict__ flag,
    int* __restrict__ cursor, unsigned short* __restrict__ msg, int E) {
  __shared__ unsigned short o_s[128 * LDP];   // epilogue staging only (34816 B)
  __shared__ int s_src[128];
  __shared__ int s_pos[128];
  const int tid = threadIdx.x;
  const long long e0 = (long long)blockIdx.x * 128;
  const int is64 = *flag;

  if (tid < 128) {
    long long e = e0 + tid;
    int s = 0, p = 0;
    if (e < E) {
      s = idx_at(ei, e, is64);
      int d = idx_at(ei, (long long)E + e, is64);
      p = atomicAdd(&cursor[d], 1);
    }
    s_src[tid] = s; s_pos[tid] = p;
  }

  const int lane = tid & 63, w = tid >> 6;
  const int l15 = lane & 15, lg = lane >> 4;

  // A fragments from global (streaming, edge order)
  float4 af[2][4][2];
#pragma unroll
  for (int mt = 0; mt < 2; ++mt) {
    long long row = e0 + w * 32 + mt * 16 + l15;
    const float* src = &ea[(row < E ? row : e0) * HD + lg * 8];
#pragma unroll
    for (int kk = 0; kk < 4; ++kk) {
      af[mt][kk][0] = *(const float4*)&src[kk * 32];
      af[mt][kk][1] = *(const float4*)&src[kk * 32 + 4];
    }
  }
  bf16x8 a[2][4];
#pragma unroll
  for (int mt = 0; mt < 2; ++mt)
#pragma unroll
    for (int kk = 0; kk < 4; ++kk) {
      float4 f0 = af[mt][kk][0], f1 = af[mt][kk][1];
      bf16x8 t;
      t[0] = (__bf16)f0.x; t[1] = (__bf16)f0.y; t[2] = (__bf16)f0.z; t[3] = (__bf16)f0.w;
      t[4] = (__bf16)f1.x; t[5] = (__bf16)f1.y; t[6] = (__bf16)f1.z; t[7] = (__bf16)f1.w;
      a[mt][kk] = t;
    }

  // MFMA, B fragments straight from L2-hot global bf16 We[128][128]
  f32x4 acc[2][8];
#pragma unroll
  for (int mt = 0; mt < 2; ++mt)
#pragma unroll
    for (int nt = 0; nt < 8; ++nt) acc[mt][nt] = (f32x4){0.f, 0.f, 0.f, 0.f};
#pragma unroll
  for (int kk = 0; kk < 4; ++kk) {
    bf16x8 b[8];
#pragma unroll
    for (int nt = 0; nt < 8; ++nt)
      b[nt] = *(const bf16x8*)&we_bf[(nt * 16 + l15) * 128 + kk * 32 + lg * 8];
#pragma unroll
    for (int mt = 0; mt < 2; ++mt)
#pragma unroll
      for (int nt = 0; nt < 8; ++nt)
        acc[mt][nt] = __builtin_amdgcn_mfma_f32_16x16x32_bf16(a[mt][kk], b[nt], acc[mt][nt], 0, 0, 0);
  }

  float bev[8];
#pragma unroll
  for (int nt = 0; nt < 8; ++nt) bev[nt] = be[nt * 16 + l15];

  // epilogue 1: (gemm + be) -> LDS bf16 (own rows, no sync needed before)
#pragma unroll
  for (int mt = 0; mt < 2; ++mt)
#pragma unroll
    for (int r = 0; r < 4; ++r) {
      int m = w * 32 + mt * 16 + lg * 4 + r;
#pragma unroll
      for (int nt = 0; nt < 8; ++nt)
        o_s[m * LDP + nt * 16 + l15] = f2bf(acc[mt][nt][r] + bev[nt]);
    }
  __syncthreads();   // the ONLY barrier: LDS rows + s_src/s_pos now visible

  // epilogue 2: bf16 x-row add + relu + CSR msg write (256B/row)
  for (int i = tid; i < 128 * 16; i += 256) {
    int r = i >> 4, sg = i & 15;
    if (e0 + r >= E) continue;
    bf16x8 xv = *(const bf16x8*)&x_bf[(size_t)s_src[r] * HD + sg * 8];
    bf16x8 g = *(const bf16x8*)&o_s[r * LDP + sg * 8];
    u16x4 h0, h1;
#pragma unroll
    for (int k = 0; k < 4; ++k) {
      float v = (float)g[k] + (float)xv[k];
      h0[k] = f2bf(v > 0.f ? v : 0.f);
    }
#pragma unroll
    for (int k = 0; k < 4; ++k) {
      float v = (float)g[4 + k] + (float)xv[4 + k];
      h1[k] = f2bf(v > 0.f ? v : 0.f);
    }
    unsigned short* mp = &msg[(size_t)s_pos[r] * 128 + sg * 8];
    *(u16x4*)&mp[0] = h0;
    *(u16x4*)&mp[4] = h1;
  }
}

// -------- gather kernel: sequential segment reads, unroll-8 -------------
__global__ __launch_bounds__(256) void gather_kernel(
    const unsigned short* __restrict__ x_bf, const int* __restrict__ off,
    const unsigned short* __restrict__ msg, unsigned short* __restrict__ h_bf,
    int N) {
  const int tid = threadIdx.x;
  const int grp = tid >> 4, li = tid & 15;
  const long long row = (long long)blockIdx.x * 16 + grp;
  if (row >= N) return;
  const int co = li * 8;
  float a8[8];
  bf16x8 xv = *(const bf16x8*)&x_bf[row * HD + co];
#pragma unroll
  for (int k = 0; k < 8; ++k) a8[k] = (float)xv[k];
  const int j0 = off[row], j1 = off[row + 1];
  int j = j0;
  for (; j + 7 < j1; j += 8) {
    bf16x8 v[8];
#pragma unroll
    for (int q = 0; q < 8; ++q)
      v[q] = *(const bf16x8*)&msg[(size_t)(j + q) * 128 + co];
#pragma unroll
    for (int k = 0; k < 8; ++k)
      a8[k] += (((float)v[0][k] + (float)v[1][k]) + ((float)v[2][k] + (float)v[3][k])) +
               (((float)v[4][k] + (float)v[5][k]) + ((float)v[6][k] + (float)v[7][k]));
  }
  for (; j < j1; ++j) {
    bf16x8 v0 = *(const bf16x8*)&msg[(size_t)j * 128 + co];
#pragma unroll
    for (int k = 0; k < 8; ++k) a8[k] += (float)v0[k];
  }
  bf16x8 hv;
#pragma unroll
  for (int k = 0; k < 8; ++k) hv[k] = (__bf16)a8[k];
  *(bf16x8*)&h_bf[row * HD + co] = hv;
}

// -------- mlp kernel: xo = LN1(x + mlp(h)) -------------------
__global__ __launch_bounds__(256, 4) void mlp_kernel(
    const float* __restrict__ x, float* __restrict__ xo,
    const unsigned short* __restrict__ h_bf,
    const unsigned short* __restrict__ W1b, const float* __restrict__ b1,
    const unsigned short* __restrict__ W2b, const float* __restrict__ b2,
    const float* __restrict__ g1, const float* __restrict__ bt1, int N) {
  __shared__ unsigned short a_s[128 * LDP];
  const int tid = threadIdx.x;
  const long long r0 = (long long)blockIdx.x * 128;

  for (int i = tid; i < 2048; i += 256) {
    int r = i >> 4, c = (i & 15) << 3;
    long long gr = r0 + r;
    bf16x8 v;
    if (gr < N) v = *(const bf16x8*)&h_bf[gr * HD + c];
    else {
#pragma unroll
      for (int k = 0; k < 8; ++k) v[k] = (__bf16)0.f;
    }
    *(bf16x8*)&a_s[r * LDP + c] = v;
  }
  __syncthreads();

  const int lane = tid & 63, w = tid >> 6;
  const int l15 = lane & 15, lg = lane >> 4;
  f32x4 acc[2][8];
#pragma unroll
  for (int mt = 0; mt < 2; ++mt)
#pragma unroll
    for (int nt = 0; nt < 8; ++nt) acc[mt][nt] = (f32x4){0.f, 0.f, 0.f, 0.f};
  mfma_tile_gb(a_s, W1b, 128, w, l15, lg, acc);
  __syncthreads();

#pragma unroll
  for (int mt = 0; mt < 2; ++mt)
#pragma unroll
    for (int r = 0; r < 4; ++r) {
      int m = w * 32 + mt * 16 + lg * 4 + r;
#pragma unroll
      for (int nt = 0; nt < 8; ++nt) {
        int n = nt * 16 + l15;
        float t = acc[mt][nt][r] + b1[n];
        a_s[m * LDP + n] = f2bf(t > 0.f ? t : 0.f);
      }
    }
  __syncthreads();

  f32x4 acc2[2][8];
#pragma unroll
  for (int mt = 0; mt < 2; ++mt)
#pragma unroll
    for (int nt = 0; nt < 8; ++nt) acc2[mt][nt] = (f32x4){0.f, 0.f, 0.f, 0.f};
  mfma_tile_gb(a_s, W2b, 128, w, l15, lg, acc2);
  __syncthreads();

#pragma unroll
  for (int mt = 0; mt < 2; ++mt)
#pragma unroll
    for (int r = 0; r < 4; ++r) {
      int m = w * 32 + mt * 16 + lg * 4 + r;
      if (r0 + m < N) {
#pragma unroll
        for (int nt = 0; nt < 8; ++nt) {
          int n = nt * 16 + l15;
          a_s[m * LDP + n] = f2bf(x[(r0 + m) * HD + n] + acc2[mt][nt][r] + b2[n]);
        }
      }
    }
  __syncthreads();

  for (int row = w; row < 128; row += 4) {
    if (r0 + row >= N) continue;
    float v1 = bf2f(a_s[row * LDP + lane]), v2 = bf2f(a_s[row * LDP + 64 + lane]);
    float s = v1 + v2, sq = v1 * v1 + v2 * v2;
    for (int o = 32; o > 0; o >>= 1) { s += __shfl_xor(s, o); sq += __shfl_xor(sq, o); }
    float mean = s * (1.f / 128.f);
    float var = sq * (1.f / 128.f) - mean * mean;
    float rs = rsqrtf(var + 1e-5f);
    xo[(r0 + row) * HD + lane]      = (v1 - mean) * rs * g1[lane] + bt1[lane];
    xo[(r0 + row) * HD + 64 + lane] = (v2 - mean) * rs * g1[lane + 64] + bt1[lane + 64];
  }
}

// ======== FUSED chem kernel: qkv -> 4-head attn -> oproj+LN2 -> ffn1 -> ffn2 ======
__global__ __launch_bounds__(256) void chem_kernel(
    float* __restrict__ xo,
    const unsigned short* __restrict__ inwb, const float* __restrict__ in_b,
    const unsigned short* __restrict__ wob, const float* __restrict__ bo,
    const float* __restrict__ g2, const float* __restrict__ bt2,
    const unsigned short* __restrict__ f1wb, const float* __restrict__ f1b,
    const unsigned short* __restrict__ f2wb, const float* __restrict__ f2b,
    const void* __restrict__ chem, const int* __restrict__ flag) {
  __shared__ unsigned short xc_s[128 * LDP];  // xc -> P -> h2
  __shared__ unsigned short q_s[128 * LDP];   // q  -> O -> u[0:128]
  __shared__ unsigned short k_s[128 * LDP];   // k  -> y stash (bf16)
  __shared__ unsigned short vt_s[128 * LDP];  // v^T -> u[128:256]
  __shared__ int s_row[128];
  const int tid = threadIdx.x, chunk = blockIdx.x;
  const int is64 = *flag;
  if (tid < 128) s_row[tid] = idx_at(chem, (long long)chunk * 128 + tid, is64);
  __syncthreads();

  for (int i = tid; i < 2048; i += 256) {
    int r = i >> 4, c = (i & 15) << 3;
    const float* src = &xo[(size_t)s_row[r] * HD + c];
    float4 f0 = *(const float4*)&src[0];
    float4 f1 = *(const float4*)&src[4];
    u16x4 h0 = { f2bf(f0.x), f2bf(f0.y), f2bf(f0.z), f2bf(f0.w) };
    u16x4 h1 = { f2bf(f1.x), f2bf(f1.y), f2bf(f1.z), f2bf(f1.w) };
    *(u16x4*)&xc_s[r * LDP + c] = h0;
    *(u16x4*)&xc_s[r * LDP + c + 4] = h1;
  }
  __syncthreads();

  const int lane = tid & 63, w = tid >> 6;
  const int l15 = lane & 15, lg = lane >> 4;
  const float scale = 0.1767766952966369f;

  for (int sec = 0; sec < 3; ++sec) {
    f32x4 acc[2][8];
#pragma unroll
    for (int mt = 0; mt < 2; ++mt)
#pragma unroll
      for (int nt = 0; nt < 8; ++nt) acc[mt][nt] = (f32x4){0.f, 0.f, 0.f, 0.f};
    mfma_tile_gb(xc_s, inwb + (size_t)sec * 128 * 128, 128, w, l15, lg, acc);
#pragma unroll
    for (int mt = 0; mt < 2; ++mt)
#pragma unroll
      for (int r = 0; r < 4; ++r) {
        int m = w * 32 + mt * 16 + lg * 4 + r;
#pragma unroll
        for (int nt = 0; nt < 8; ++nt) {
          int n = nt * 16 + l15;
          float t = acc[mt][nt][r] + in_b[sec * 128 + n];
          if (sec == 0)      q_s[m * LDP + n] = f2bf(t * scale);
          else if (sec == 1) k_s[m * LDP + n] = f2bf(t);
          else               vt_s[n * LDP + m] = f2bf(t);
        }
      }
  }
  __syncthreads();

  f32x4 oacc[2][8];
#pragma unroll
  for (int mt = 0; mt < 2; ++mt)
#pragma unroll
    for (int nt = 0; nt < 8; ++nt) oacc[mt][nt] = (f32x4){0.f, 0.f, 0.f, 0.f};

  for (int h = 0; h < 4; ++h) {
    f32x4 sacc[2][8];
#pragma unroll
    for (int mt = 0; mt < 2; ++mt)
#pragma unroll
      for (int nt = 0; nt < 8; ++nt) sacc[mt][nt] = (f32x4){0.f, 0.f, 0.f, 0.f};
    {
      bf16x8 a[2], b[8];
#pragma unroll
      for (int mt = 0; mt < 2; ++mt)
        a[mt] = *(const bf16x8*)&q_s[(w * 32 + mt * 16 + l15) * LDP + h * 32 + lg * 8];
#pragma unroll
      for (int nt = 0; nt < 8; ++nt)
        b[nt] = *(const bf16x8*)&k_s[(nt * 16 + l15) * LDP + h * 32 + lg * 8];
#pragma unroll
      for (int mt = 0; mt < 2; ++mt)
#pragma unroll
        for (int nt = 0; nt < 8; ++nt)
          sacc[mt][nt] = __builtin_amdgcn_mfma_f32_16x16x32_bf16(a[mt], b[nt], sacc[mt][nt], 0, 0, 0);
    }
#pragma unroll
    for (int mt = 0; mt < 2; ++mt)
#pragma unroll
      for (int r = 0; r < 4; ++r) {
        int m = w * 32 + mt * 16 + lg * 4 + r;
        float mx = -1e30f;
#pragma unroll
        for (int nt = 0; nt < 8; ++nt) mx = fmaxf(mx, sacc[mt][nt][r]);
        for (int o = 8; o > 0; o >>= 1) mx = fmaxf(mx, __shfl_xor(mx, o));
        float sm = 0.f;
        float p[8];
#pragma unroll
        for (int nt = 0; nt < 8; ++nt) { p[nt] = __expf(sacc[mt][nt][r] - mx); sm += p[nt]; }
        for (int o = 8; o > 0; o >>= 1) sm += __shfl_xor(sm, o);
        float inv = 1.f / sm;
#pragma unroll
        for (int nt = 0; nt < 8; ++nt)
          xc_s[m * LDP + nt * 16 + l15] = f2bf(p[nt] * inv);
      }
#pragma unroll
    for (int kk = 0; kk < 4; ++kk) {
      bf16x8 pa[2], vb[2];
#pragma unroll
      for (int mt = 0; mt < 2; ++mt)
        pa[mt] = *(const bf16x8*)&xc_s[(w * 32 + mt * 16 + l15) * LDP + kk * 32 + lg * 8];
#pragma unroll
      for (int nt2 = 0; nt2 < 2; ++nt2)
        vb[nt2] = *(const bf16x8*)&vt_s[(h * 32 + nt2 * 16 + l15) * LDP + kk * 32 + lg * 8];
#pragma unroll
      for (int mt = 0; mt < 2; ++mt)
#pragma unroll
        for (int nt2 = 0; nt2 < 2; ++nt2)
          oacc[mt][h * 2 + nt2] =
              __builtin_amdgcn_mfma_f32_16x16x32_bf16(pa[mt], vb[nt2], oacc[mt][h * 2 + nt2], 0, 0, 0);
    }
  }
  __syncthreads();

#pragma unroll
  for (int mt = 0; mt < 2; ++mt)
#pragma unroll
    for (int r = 0; r < 4; ++r) {
      int m = w * 32 + mt * 16 + lg * 4 + r;
#pragma unroll
      for (int nt = 0; nt < 8; ++nt)
        q_s[m * LDP + nt * 16 + l15] = f2bf(oacc[mt][nt][r]);
    }

  f32x4 pacc[2][8];
#pragma unroll
  for (int mt = 0; mt < 2; ++mt)
#pragma unroll
    for (int nt = 0; nt < 8; ++nt) pacc[mt][nt] = (f32x4){0.f, 0.f, 0.f, 0.f};
  mfma_tile_gb(q_s, wob, 128, w, l15, lg, pacc);

#pragma unroll
  for (int mt = 0; mt < 2; ++mt)
#pragma unroll
    for (int r = 0; r < 4; ++r) {
      int m = w * 32 + mt * 16 + lg * 4 + r;
      const float* xrow = &xo[(size_t)s_row[m] * HD];
      float y[8];
      float s = 0.f, sq = 0.f;
#pragma unroll
      for (int nt = 0; nt < 8; ++nt) {
        int n = nt * 16 + l15;
        y[nt] = xrow[n] + pacc[mt][nt][r] + bo[n];
        s += y[nt]; sq += y[nt] * y[nt];
      }
      for (int o = 8; o > 0; o >>= 1) { s += __shfl_xor(s, o); sq += __shfl_xor(sq, o); }
      float mean = s * (1.f / 128.f);
      float var = sq * (1.f / 128.f) - mean * mean;
      float rs = rsqrtf(var + 1e-5f);
#pragma unroll
      for (int nt = 0; nt < 8; ++nt) {
        int n = nt * 16 + l15;
        xc_s[m * LDP + n] = f2bf((y[nt] - mean) * rs * g2[n] + bt2[n]);
        k_s[m * LDP + n]  = f2bf(y[nt]);
      }
    }

  for (int sec = 0; sec < 2; ++sec) {
    f32x4 acc[2][8];
#pragma unroll
    for (int mt = 0; mt < 2; ++mt)
#pragma unroll
      for (int nt = 0; nt < 8; ++nt) acc[mt][nt] = (f32x4){0.f, 0.f, 0.f, 0.f};
    mfma_tile_gb(xc_s, f1wb + (size_t)sec * 128 * 128, 128, w, l15, lg, acc);
    unsigned short* ub = (sec == 0) ? q_s : vt_s;
#pragma unroll
    for (int mt = 0; mt < 2; ++mt)
#pragma unroll
      for (int r = 0; r < 4; ++r) {
        int m = w * 32 + mt * 16 + lg * 4 + r;
#pragma unroll
        for (int nt = 0; nt < 8; ++nt) {
          int n = nt * 16 + l15;
          float t = acc[mt][nt][r] + f1b[sec * 128 + n];
          ub[m * LDP + n] = f2bf(t > 0.f ? t : 0.f);
        }
      }
  }

  f32x4 facc[2][8];
#pragma unroll
  for (int mt = 0; mt < 2; ++mt)
#pragma unroll
    for (int nt = 0; nt < 8; ++nt) facc[mt][nt] = (f32x4){0.f, 0.f, 0.f, 0.f};
  mfma_tile_gb(q_s, f2wb, 256, w, l15, lg, facc);
  mfma_tile_gb(vt_s, f2wb + 128, 256, w, l15, lg, facc);

#pragma unroll
  for (int mt = 0; mt < 2; ++mt)
#pragma unroll
    for (int r = 0; r < 4; ++r) {
      int m = w * 32 + mt * 16 + lg * 4 + r;
      float* orow = &xo[(size_t)s_row[m] * HD];
#pragma unroll
      for (int nt = 0; nt < 8; ++nt) {
        int n = nt * 16 + l15;
        orow[n] = bf2f(k_s[m * LDP + n]) + facc[mt][nt][r] + f2b[n];
      }
    }
}

// ================= FALLBACK (small ws): atomic edge + fused node =================
__global__ __launch_bounds__(256) void edge_kernel(
    const float* __restrict__ x, const float* __restrict__ ea,
    const float* __restrict__ We, const float* __restrict__ be,
    const void* __restrict__ ei, const int* __restrict__ flag,
    float* __restrict__ agg, int E, int N) {
  __shared__ unsigned short ea_s[128 * LDP];
  __shared__ unsigned short we_s[128 * LDP];
  __shared__ int s_src[128];
  __shared__ int s_dst[128];
  const int tid = threadIdx.x;
  const long long e0 = (long long)blockIdx.x * 128;
  const int is64 = *flag;
  if (tid < 128) {
    long long e = e0 + tid;
    int s = 0, d = 0;
    if (e < E) { s = idx_at(ei, e, is64); d = idx_at(ei, (long long)E + e, is64); }
    s_src[tid] = s; s_dst[tid] = d;
  }
  for (int i = tid; i < 128 * 32; i += 256) {
    int r = i >> 5, c = (i & 31) << 2;
    float4 f = {0.f, 0.f, 0.f, 0.f};
    if (e0 + r < E) f = *(const float4*)&ea[(e0 + r) * HD + c];
    u16x4 h = { f2bf(f.x), f2bf(f.y), f2bf(f.z), f2bf(f.w) };
    *(u16x4*)&ea_s[r * LDP + c] = h;
    float4 g = *(const float4*)&We[r * HD + c];
    u16x4 hw = { f2bf(g.x), f2bf(g.y), f2bf(g.z), f2bf(g.w) };
    *(u16x4*)&we_s[r * LDP + c] = hw;
  }
  __syncthreads();
  const int lane = tid & 63, w = tid >> 6;
  const int l15 = lane & 15, lg = lane >> 4;
  f32x4 acc[2][8];
#pragma unroll
  for (int mt = 0; mt < 2; ++mt)
#pragma unroll
    for (int nt = 0; nt < 8; ++nt) acc[mt][nt] = (f32x4){0.f, 0.f, 0.f, 0.f};
  mfma_tile_128(ea_s, we_s, w, l15, lg, acc);
  float bev[8];
#pragma unroll
  for (int nt = 0; nt < 8; ++nt) bev[nt] = be[nt * 16 + l15];
#pragma unroll
  for (int mt = 0; mt < 2; ++mt) {
#pragma unroll
    for (int r = 0; r < 4; ++r) {
      int m = w * 32 + mt * 16 + lg * 4 + r;
      if (e0 + m >= E) continue;
      const float* xrow = x + (size_t)s_src[m] * HD;
      float* arow = agg + (size_t)s_dst[m] * HD;
#pragma unroll
      for (int nt = 0; nt < 8; ++nt) {
        int n = nt * 16 + l15;
        float val = acc[mt][nt][r] + bev[nt] + xrow[n];
        if (val > 0.f) unsafeAtomicAdd(&arow[n], val);
      }
    }
  }
}

__global__ __launch_bounds__(256) void node_kernel(
    const float* __restrict__ x, float* xo,
    const float* __restrict__ W1, const float* __restrict__ b1,
    const float* __restrict__ W2, const float* __restrict__ b2,
    const float* __restrict__ g1, const float* __restrict__ bt1, int N) {
  __shared__ char smem[2 * 128 * LDP * 2];
  unsigned short* a_s = (unsigned short*)smem;
  unsigned short* w_s = (unsigned short*)smem + 128 * LDP;
  float* y_s = (float*)smem;
  const int tid = threadIdx.x;
  const long long r0 = (long long)blockIdx.x * 128;
  for (int i = tid; i < 128 * 32; i += 256) {
    int r = i >> 5, c = (i & 31) << 2;
    float4 f = {0.f, 0.f, 0.f, 0.f};
    if (r0 + r < N) {
      float4 xa = *(const float4*)&x[(r0 + r) * HD + c];
      float4 ag = *(const float4*)&xo[(r0 + r) * HD + c];
      f.x = xa.x + ag.x; f.y = xa.y + ag.y; f.z = xa.z + ag.z; f.w = xa.w + ag.w;
    }
    u16x4 h = { f2bf(f.x), f2bf(f.y), f2bf(f.z), f2bf(f.w) };
    *(u16x4*)&a_s[r * LDP + c] = h;
    float4 g = *(const float4*)&W1[r * HD + c];
    u16x4 hw = { f2bf(g.x), f2bf(g.y), f2bf(g.z), f2bf(g.w) };
    *(u16x4*)&w_s[r * LDP + c] = hw;
  }
  __syncthreads();
  const int lane = tid & 63, w = tid >> 6;
  const int l15 = lane & 15, lg = lane >> 4;
  f32x4 acc[2][8];
#pragma unroll
  for (int mt = 0; mt < 2; ++mt)
#pragma unroll
    for (int nt = 0; nt < 8; ++nt) acc[mt][nt] = (f32x4){0.f, 0.f, 0.f, 0.f};
  mfma_tile_128(a_s, w_s, w, l15, lg, acc);
  __syncthreads();
#pragma unroll
  for (int mt = 0; mt < 2; ++mt)
#pragma unroll
    for (int r = 0; r < 4; ++r) {
      int m = w * 32 + mt * 16 + lg * 4 + r;
#pragma unroll
      for (int nt = 0; nt < 8; ++nt) {
        int n = nt * 16 + l15;
        float t = acc[mt][nt][r] + b1[n];
        a_s[m * LDP + n] = f2bf(t > 0.f ? t : 0.f);
      }
    }
  stage_f32s(w_s, W2, HD, tid, 256);
  __syncthreads();
  f32x4 acc2[2][8];
#pragma unroll
  for (int mt = 0; mt < 2; ++mt)
#pragma unroll
    for (int nt = 0; nt < 8; ++nt) acc2[mt][nt] = (f32x4){0.f, 0.f, 0.f, 0.f};
  mfma_tile_128(a_s, w_s, w, l15, lg, acc2);
  __syncthreads();
#pragma unroll
  for (int mt = 0; mt < 2; ++mt)
#pragma unroll
    for (int r = 0; r < 4; ++r) {
      int m = w * 32 + mt * 16 + lg * 4 + r;
      if (r0 + m < N) {
#pragma unroll
        for (int nt = 0; nt < 8; ++nt) {
          int n = nt * 16 + l15;
          y_s[m * 132 + n] = x[(r0 + m) * HD + n] + acc2[mt][nt][r] + b2[n];
        }
      }
    }
  __syncthreads();
  for (int row = w; row < 128; row += 4) {
    if (r0 + row >= N) continue;
    float v1 = y_s[row * 132 + lane], v2 = y_s[row * 132 + 64 + lane];
    float s = v1 + v2, sq = v1 * v1 + v2 * v2;
    for (int o = 32; o > 0; o >>= 1) { s += __shfl_xor(s, o); sq += __shfl_xor(sq, o); }
    float mean = s * (1.f / 128.f);
    float var = sq * (1.f / 128.f) - mean * mean;
    float rs = rsqrtf(var + 1e-5f);
    xo[(r0 + row) * HD + lane]      = (v1 - mean) * rs * g1[lane] + bt1[lane];
    xo[(r0 + row) * HD + 64 + lane] = (v2 - mean) * rs * g1[lane + 64] + bt1[lane + 64];
  }
}

extern "C" void kernel_launch(void* const* d_in, const int* in_sizes, int n_in,
                              void* d_out, int out_size, void* d_ws, size_t ws_size,
                              hipStream_t stream) {
  const float* x    = (const float*)d_in[0];
  const float* ea   = (const float*)d_in[1];
  const float* We   = (const float*)d_in[2];
  const float* be   = (const float*)d_in[3];
  const float* W1   = (const float*)d_in[4];
  const float* b1   = (const float*)d_in[5];
  const float* W2   = (const float*)d_in[6];
  const float* b2   = (const float*)d_in[7];
  const float* g1   = (const float*)d_in[8];
  const float* bt1  = (const float*)d_in[9];
  const float* in_w = (const float*)d_in[10];
  const float* in_b = (const float*)d_in[11];
  const float* outw = (const float*)d_in[12];
  const float* outb = (const float*)d_in[13];
  const float* g2   = (const float*)d_in[14];
  const float* bt2  = (const float*)d_in[15];
  const float* f1w  = (const float*)d_in[16];
  const float* f1b  = (const float*)d_in[17];
  const float* f2w  = (const float*)d_in[18];
  const float* f2b  = (const float*)d_in[19];
  const void*  ei   = d_in[20];
  const void*  chem = d_in[21];
  const int N  = in_sizes[0] / HD;
  const int E  = in_sizes[1] / HD;
  const int NC = in_sizes[21];
  const int NB = (N + SCH - 1) / SCH;
  float* xo = (float*)d_out;

  char* ws = (char*)d_ws;
  size_t o = 0;
  auto alloc = [&](size_t bytes) { size_t p = o; o = (o + bytes + 255) & ~255ULL; return p; };
  size_t o_flag = alloc(4);
  size_t o_webf = alloc(128 * 128 * 2);
  size_t o_w1b  = alloc(128 * 128 * 2);
  size_t o_w2b  = alloc(128 * 128 * 2);
  size_t o_inwb = alloc(384 * 128 * 2);
  size_t o_wob  = alloc(128 * 128 * 2);
  size_t o_f1wb = alloc(256 * 128 * 2);
  size_t o_f2wb = alloc(128 * 256 * 2);
  size_t o_xbf  = alloc((size_t)N * 128 * 2);
  size_t o_hbf  = alloc((size_t)N * 128 * 2);
  size_t o_deg  = alloc((size_t)N * 4);
  size_t o_off  = alloc((size_t)(N + 1) * 4);
  size_t o_cur  = alloc((size_t)N * 4);
  size_t o_bsum = alloc((size_t)NB * 4);
  size_t o_msg  = alloc((size_t)E * 128 * 2);
  size_t need = o;

  int*            flag = (int*)(ws + o_flag);
  unsigned short* webf = (unsigned short*)(ws + o_webf);
  unsigned short* w1b  = (unsigned short*)(ws + o_w1b);
  unsigned short* w2b  = (unsigned short*)(ws + o_w2b);
  unsigned short* inwb = (unsigned short*)(ws + o_inwb);
  unsigned short* wob  = (unsigned short*)(ws + o_wob);
  unsigned short* f1wb = (unsigned short*)(ws + o_f1wb);
  unsigned short* f2wb = (unsigned short*)(ws + o_f2wb);
  unsigned short* xbf  = (unsigned short*)(ws + o_xbf);
  unsigned short* hbf  = (unsigned short*)(ws + o_hbf);
  int*            deg  = (int*)(ws + o_deg);
  int*            off  = (int*)(ws + o_off);
  int*            cur  = (int*)(ws + o_cur);
  int*            bsum = (int*)(ws + o_bsum);
  unsigned short* msg  = (unsigned short*)(ws + o_msg);

  detect_idx_kernel<<<1, 64, 0, stream>>>(ei, E, N, flag);
  conv_weights_kernel<<<dim3(640), 256, 0, stream>>>(W1, W2, in_w, outw, f1w, f2w,
                                                     w1b, w2b, inwb, wob, f1wb, f2wb);

  if (ws_size >= need) {
    hipMemsetAsync(deg, 0, (size_t)N * 4, stream);
    conv_x_kernel<<<dim3((N * 16 + 255) / 256), 256, 0, stream>>>(x, xbf, (long long)N * 16);
    hist_kernel<<<dim3(1024), 256, 0, stream>>>(ei, flag, deg, E);
    scan_a<<<dim3(NB), 256, 0, stream>>>(deg, bsum, N);
    if (NB <= 128) scan_b2<<<1, 128, 0, stream>>>(bsum, off, NB, N);
    else           scan_b<<<1, 64, 0, stream>>>(bsum, off, NB, N);
    scan_c<<<dim3(NB), 256, 0, stream>>>(deg, bsum, off, cur, N);
    conv_we_kernel<<<dim3(64), 256, 0, stream>>>(We, webf);
    edge_kernel12<<<dim3((E + 127) / 128), 256, 0, stream>>>(xbf, ea, webf, be, ei,
                                                             flag, cur, msg, E);
    gather_kernel<<<dim3((N + 15) / 16), 256, 0, stream>>>(xbf, off, msg, hbf, N);
    mlp_kernel<<<dim3((N + 127) / 128), 256, 0, stream>>>(x, xo, hbf, w1b, b1, w2b,
                                                          b2, g1, bt1, N);
  } else {
    hipMemsetAsync(xo, 0, (size_t)N * HD * sizeof(float), stream);
    edge_kernel<<<dim3((E + 127) / 128), 256, 0, stream>>>(x, ea, We, be, ei, flag, xo, E, N);
    node_kernel<<<dim3((N + 127) / 128), 256, 0, stream>>>(x, xo, W1, b1, W2, b2, g1, bt1, N);
  }

  chem_kernel<<<dim3(NC / 128), 256, 0, stream>>>(xo, inwb, in_b, wob, outb, g2, bt2,
                                                  f1wb, f1b, f2wb, f2b, chem, flag);
}

// Round 13
// 722.773 us; speedup vs baseline: 1.0921x; 1.0921x over previous
//
#include <hip/hip_runtime.h>
#include <hip/hip_bf16.h>
#include <math.h>

typedef __attribute__((ext_vector_type(8))) __bf16 bf16x8;
typedef __attribute__((ext_vector_type(4))) float f32x4;
typedef __attribute__((ext_vector_type(4))) unsigned short u16x4;

#define HD  128
#define LDP 136

__device__ __forceinline__ unsigned short f2bf(float f) {
  __bf16 h = (__bf16)f;
  union { __bf16 h; unsigned short u; } v; v.h = h; return v.u;
}
__device__ __forceinline__ float bf2f(unsigned short h) {
  union { unsigned u; float f; } v; v.u = ((unsigned)h) << 16; return v.f;
}

__device__ __forceinline__ int idx_at(const void* p, long long i, int is64) {
  if (is64) return (int)((const long long*)p)[i];
  return ((const int*)p)[i];
}

// 128x128 += A(LDS bf16 LDP) @ B^T(LDS bf16 LDP). wave w: rows [w*32,w*32+32)
// D: m = w*32+mt*16+(lane>>4)*4+r, n = nt*16+(lane&15)
__device__ __forceinline__ void mfma_tile_128(const unsigned short* a_s,
                                              const unsigned short* w_s,
                                              int w, int l15, int lg,
                                              f32x4 acc[2][8]) {
#pragma unroll
  for (int kk = 0; kk < 4; ++kk) {
    bf16x8 a[2], b[8];
#pragma unroll
    for (int mt = 0; mt < 2; ++mt)
      a[mt] = *(const bf16x8*)&a_s[(w * 32 + mt * 16 + l15) * LDP + kk * 32 + lg * 8];
#pragma unroll
    for (int nt = 0; nt < 8; ++nt)
      b[nt] = *(const bf16x8*)&w_s[(nt * 16 + l15) * LDP + kk * 32 + lg * 8];
#pragma unroll
    for (int mt = 0; mt < 2; ++mt)
#pragma unroll
      for (int nt = 0; nt < 8; ++nt)
        acc[mt][nt] = __builtin_amdgcn_mfma_f32_16x16x32_bf16(a[mt], b[nt], acc[mt][nt], 0, 0, 0);
  }
}

// B fragments from GLOBAL bf16 [128][ldw] (L2-hot weights)
__device__ __forceinline__ void mfma_tile_gb(const unsigned short* a_s,
                                             const unsigned short* Wb, int ldw,
                                             int w, int l15, int lg,
                                             f32x4 acc[2][8]) {
#pragma unroll
  for (int kk = 0; kk < 4; ++kk) {
    bf16x8 a[2], b[8];
#pragma unroll
    for (int mt = 0; mt < 2; ++mt)
      a[mt] = *(const bf16x8*)&a_s[(w * 32 + mt * 16 + l15) * LDP + kk * 32 + lg * 8];
#pragma unroll
    for (int nt = 0; nt < 8; ++nt)
      b[nt] = *(const bf16x8*)&Wb[(size_t)(nt * 16 + l15) * ldw + kk * 32 + lg * 8];
#pragma unroll
    for (int mt = 0; mt < 2; ++mt)
#pragma unroll
      for (int nt = 0; nt < 8; ++nt)
        acc[mt][nt] = __builtin_amdgcn_mfma_f32_16x16x32_bf16(a[mt], b[nt], acc[mt][nt], 0, 0, 0);
  }
}

__device__ __forceinline__ void stage_f32s(unsigned short* dst, const float* src,
                                           long long src_ld, int tid, int T) {
  for (int i = tid; i < 128 * 32; i += T) {
    int r = i >> 5, c = (i & 31) << 2;
    float4 f = *(const float4*)&src[(long long)r * src_ld + c];
    u16x4 h = { f2bf(f.x), f2bf(f.y), f2bf(f.z), f2bf(f.w) };
    *(u16x4*)&dst[r * LDP + c] = h;
  }
}

// ---------------- index dtype detector ----------------
__global__ void detect_idx_kernel(const void* __restrict__ ei, int E, int N,
                                  int* __restrict__ flag) {
  if (threadIdx.x == 0 && blockIdx.x == 0) {
    const long long* p = (const long long*)ei;
    int is64 = 1;
    long long step = E / 64; if (step < 1) step = 1;
    for (int i = 0; i < 64; ++i) {
      long long v = p[i * step];
      if (v < 0 || v >= N) { is64 = 0; break; }
    }
    *flag = is64;
  }
}

// ---------------- f32 -> bf16 pre-converts ----------------
__global__ __launch_bounds__(256) void conv_we_kernel(const float* __restrict__ We,
                                                      unsigned short* __restrict__ we_bf) {
  int i = blockIdx.x * 256 + threadIdx.x;
  if (i < 128 * 128) we_bf[i] = f2bf(We[i]);
}
__global__ __launch_bounds__(256) void conv_weights_kernel(
    const float* __restrict__ W1, const float* __restrict__ W2,
    const float* __restrict__ inw, const float* __restrict__ wo,
    const float* __restrict__ f1, const float* __restrict__ f2,
    unsigned short* __restrict__ w1b, unsigned short* __restrict__ w2b,
    unsigned short* __restrict__ inwb, unsigned short* __restrict__ wob,
    unsigned short* __restrict__ f1b, unsigned short* __restrict__ f2b) {
  int i = blockIdx.x * 256 + threadIdx.x;
  if (i < 16384) w1b[i] = f2bf(W1[i]);
  else if (i < 32768) w2b[i - 16384] = f2bf(W2[i - 16384]);
  else if (i < 81920) inwb[i - 32768] = f2bf(inw[i - 32768]);
  else if (i < 98304) wob[i - 81920] = f2bf(wo[i - 81920]);
  else if (i < 131072) f1b[i - 98304] = f2bf(f1[i - 98304]);
  else if (i < 163840) f2b[i - 131072] = f2bf(f2[i - 131072]);
}
__global__ __launch_bounds__(256) void conv_x_kernel(const float* __restrict__ x,
                                                     unsigned short* __restrict__ xb,
                                                     long long n8) {
  long long i = blockIdx.x * 256LL + threadIdx.x;
  if (i < n8) {
    float4 f0 = *(const float4*)&x[i * 8];
    float4 f1 = *(const float4*)&x[i * 8 + 4];
    u16x4 h0 = { f2bf(f0.x), f2bf(f0.y), f2bf(f0.z), f2bf(f0.w) };
    u16x4 h1 = { f2bf(f1.x), f2bf(f1.y), f2bf(f1.z), f2bf(f1.w) };
    *(u16x4*)&xb[i * 8] = h0;
    *(u16x4*)&xb[i * 8 + 4] = h1;
  }
}

// ---------------- dst histogram ----------------
__global__ __launch_bounds__(256) void hist_kernel(const void* __restrict__ ei,
                                                   const int* __restrict__ flag,
                                                   int* __restrict__ deg, int E) {
  const int is64 = *flag;
  for (long long e = blockIdx.x * 256LL + threadIdx.x; e < E;
       e += (long long)gridDim.x * 256)
    atomicAdd(&deg[idx_at(ei, (long long)E + e, is64)], 1);
}

// ---------------- 3-phase exclusive scan ----------------
#define SCH 1024
__global__ __launch_bounds__(256) void scan_a(const int* __restrict__ deg,
                                              int* __restrict__ bsum, int N) {
  const int b = blockIdx.x, t = threadIdx.x;
  int p = 0;
#pragma unroll
  for (int k = 0; k < 4; ++k) {
    int idx = b * SCH + t * 4 + k;
    if (idx < N) p += deg[idx];
  }
  __shared__ int warr[4];
  for (int o = 32; o > 0; o >>= 1) p += __shfl_xor(p, o);
  if ((t & 63) == 0) warr[t >> 6] = p;
  __syncthreads();
  if (t == 0) bsum[b] = warr[0] + warr[1] + warr[2] + warr[3];
}
__global__ void scan_b(int* __restrict__ bsum, int* __restrict__ off, int NB, int N) {
  if (threadIdx.x == 0 && blockIdx.x == 0) {
    int run = 0;
    for (int b = 0; b < NB; ++b) { int t = bsum[b]; bsum[b] = run; run += t; }
    off[N] = run;
  }
}
__global__ __launch_bounds__(128) void scan_b2(int* __restrict__ bsum,
                                               int* __restrict__ off, int NB, int N) {
  __shared__ int arr[128];
  const int t = threadIdx.x;
  int v = (t < NB) ? bsum[t] : 0;
  arr[t] = v;
  __syncthreads();
  for (int s = 1; s < 128; s <<= 1) {
    int u = (t >= s) ? arr[t - s] : 0;
    __syncthreads();
    arr[t] += u;
    __syncthreads();
  }
  if (t < NB) bsum[t] = arr[t] - v;
  if (t == 0) off[N] = arr[127];
}
__global__ __launch_bounds__(256) void scan_c(const int* __restrict__ deg,
                                              const int* __restrict__ bsum,
                                              int* __restrict__ off,
                                              int* __restrict__ cursor, int N) {
  const int b = blockIdx.x, t = threadIdx.x;
  int d[4], s = 0;
#pragma unroll
  for (int k = 0; k < 4; ++k) {
    int idx = b * SCH + t * 4 + k;
    d[k] = (idx < N) ? deg[idx] : 0;
    s += d[k];
  }
  __shared__ int arr[256];
  arr[t] = s;
  __syncthreads();
  for (int stp = 1; stp < 256; stp <<= 1) {
    int v = (t >= stp) ? arr[t - stp] : 0;
    __syncthreads();
    arr[t] += v;
    __syncthreads();
  }
  int base = bsum[b] + arr[t] - s;
  int acc = 0;
#pragma unroll
  for (int k = 0; k < 4; ++k) {
    int idx = b * SCH + t * 4 + k;
    if (idx < N) { off[idx] = base + acc; cursor[idx] = base + acc; }
    acc += d[k];
  }
}

// -------- edge kernel v13: r11 structure (We in LDS) + prefetched epilogue x-rows --
__global__ __launch_bounds__(256, 4) void edge_kernel13(
    const unsigned short* __restrict__ x_bf, const float* __restrict__ ea,
    const unsigned short* __restrict__ we_bf, const float* __restrict__ be,
    const void* __restrict__ ei, const int* __restrict__ flag,
    int* __restrict__ cursor, unsigned short* __restrict__ msg, int E) {
  __shared__ unsigned short we_s[128 * LDP];   // We tile; reused as gemm-out staging
  __shared__ int s_src[128];
  __shared__ int s_pos[128];
  const int tid = threadIdx.x;
  const long long e0 = (long long)blockIdx.x * 128;
  const int is64 = *flag;

  if (tid < 128) {
    long long e = e0 + tid;
    int s = 0, p = 0;
    if (e < E) {
      s = idx_at(ei, e, is64);
      int d = idx_at(ei, (long long)E + e, is64);
      p = atomicAdd(&cursor[d], 1);
    }
    s_src[tid] = s; s_pos[tid] = p;
  }

  const int lane = tid & 63, w = tid >> 6;
  const int l15 = lane & 15, lg = lane >> 4;

  // A fragments from global (streaming, edge order)
  float4 af[2][4][2];
#pragma unroll
  for (int mt = 0; mt < 2; ++mt) {
    long long row = e0 + w * 32 + mt * 16 + l15;
    const float* src = &ea[(row < E ? row : e0) * HD + lg * 8];
#pragma unroll
    for (int kk = 0; kk < 4; ++kk) {
      af[mt][kk][0] = *(const float4*)&src[kk * 32];
      af[mt][kk][1] = *(const float4*)&src[kk * 32 + 4];
    }
  }

  // stage bf16 We [128][128] -> LDS (pure 16B copies)
  for (int i = tid; i < 2048; i += 256) {
    int r = i >> 4, c = (i & 15) << 3;
    *(float4*)&we_s[r * LDP + c] = *(const float4*)&we_bf[r * 128 + c];
  }

  bf16x8 a[2][4];
#pragma unroll
  for (int mt = 0; mt < 2; ++mt)
#pragma unroll
    for (int kk = 0; kk < 4; ++kk) {
      float4 f0 = af[mt][kk][0], f1 = af[mt][kk][1];
      bf16x8 t;
      t[0] = (__bf16)f0.x; t[1] = (__bf16)f0.y; t[2] = (__bf16)f0.z; t[3] = (__bf16)f0.w;
      t[4] = (__bf16)f1.x; t[5] = (__bf16)f1.y; t[6] = (__bf16)f1.z; t[7] = (__bf16)f1.w;
      a[mt][kk] = t;
    }
  __syncthreads();   // We staged; s_src/s_pos visible

  // PREFETCH epilogue-2 x-rows NOW: their latency overlaps the MFMA phase.
  // Thread tid handles (r,sg) = ((tid+k*256)>>4, (tid+k*256)&15) in epilogue-2.
  bf16x8 xv[8];
#pragma unroll
  for (int k = 0; k < 8; ++k) {
    int i = tid + k * 256;
    int r = i >> 4, sg = i & 15;
    int src = s_src[r];
    xv[k] = *(const bf16x8*)&x_bf[(size_t)src * HD + sg * 8];
  }

  // MFMA (B from LDS)
  f32x4 acc[2][8];
#pragma unroll
  for (int mt = 0; mt < 2; ++mt)
#pragma unroll
    for (int nt = 0; nt < 8; ++nt) acc[mt][nt] = (f32x4){0.f, 0.f, 0.f, 0.f};
#pragma unroll
  for (int kk = 0; kk < 4; ++kk) {
    bf16x8 b[8];
#pragma unroll
    for (int nt = 0; nt < 8; ++nt)
      b[nt] = *(const bf16x8*)&we_s[(nt * 16 + l15) * LDP + kk * 32 + lg * 8];
#pragma unroll
    for (int mt = 0; mt < 2; ++mt)
#pragma unroll
      for (int nt = 0; nt < 8; ++nt)
        acc[mt][nt] = __builtin_amdgcn_mfma_f32_16x16x32_bf16(a[mt][kk], b[nt], acc[mt][nt], 0, 0, 0);
  }

  float bev[8];
#pragma unroll
  for (int nt = 0; nt < 8; ++nt) bev[nt] = be[nt * 16 + l15];
  __syncthreads();   // all We reads done -> reuse we_s as gemm-out staging

  // epilogue 1: (gemm + be) -> LDS bf16 (own rows)
#pragma unroll
  for (int mt = 0; mt < 2; ++mt)
#pragma unroll
    for (int r = 0; r < 4; ++r) {
      int m = w * 32 + mt * 16 + lg * 4 + r;
#pragma unroll
      for (int nt = 0; nt < 8; ++nt)
        we_s[m * LDP + nt * 16 + l15] = f2bf(acc[mt][nt][r] + bev[nt]);
    }
  __syncthreads();

  // epilogue 2: combine prefetched x with gemm rows; relu; CSR msg write
#pragma unroll
  for (int k = 0; k < 8; ++k) {
    int i = tid + k * 256;
    int r = i >> 4, sg = i & 15;
    if (e0 + r >= E) continue;
    bf16x8 g = *(const bf16x8*)&we_s[r * LDP + sg * 8];
    u16x4 h0, h1;
#pragma unroll
    for (int q = 0; q < 4; ++q) {
      float v = (float)g[q] + (float)xv[k][q];
      h0[q] = f2bf(v > 0.f ? v : 0.f);
    }
#pragma unroll
    for (int q = 0; q < 4; ++q) {
      float v = (float)g[4 + q] + (float)xv[k][4 + q];
      h1[q] = f2bf(v > 0.f ? v : 0.f);
    }
    unsigned short* mp = &msg[(size_t)s_pos[r] * 128 + sg * 8];
    *(u16x4*)&mp[0] = h0;
    *(u16x4*)&mp[4] = h1;
  }
}

// -------- gather kernel: sequential segment reads, unroll-8 -------------
__global__ __launch_bounds__(256) void gather_kernel(
    const unsigned short* __restrict__ x_bf, const int* __restrict__ off,
    const unsigned short* __restrict__ msg, unsigned short* __restrict__ h_bf,
    int N) {
  const int tid = threadIdx.x;
  const int grp = tid >> 4, li = tid & 15;
  const long long row = (long long)blockIdx.x * 16 + grp;
  if (row >= N) return;
  const int co = li * 8;
  float a8[8];
  bf16x8 xv = *(const bf16x8*)&x_bf[row * HD + co];
#pragma unroll
  for (int k = 0; k < 8; ++k) a8[k] = (float)xv[k];
  const int j0 = off[row], j1 = off[row + 1];
  int j = j0;
  for (; j + 7 < j1; j += 8) {
    bf16x8 v[8];
#pragma unroll
    for (int q = 0; q < 8; ++q)
      v[q] = *(const bf16x8*)&msg[(size_t)(j + q) * 128 + co];
#pragma unroll
    for (int k = 0; k < 8; ++k)
      a8[k] += (((float)v[0][k] + (float)v[1][k]) + ((float)v[2][k] + (float)v[3][k])) +
               (((float)v[4][k] + (float)v[5][k]) + ((float)v[6][k] + (float)v[7][k]));
  }
  for (; j < j1; ++j) {
    bf16x8 v0 = *(const bf16x8*)&msg[(size_t)j * 128 + co];
#pragma unroll
    for (int k = 0; k < 8; ++k) a8[k] += (float)v0[k];
  }
  bf16x8 hv;
#pragma unroll
  for (int k = 0; k < 8; ++k) hv[k] = (__bf16)a8[k];
  *(bf16x8*)&h_bf[row * HD + co] = hv;
}

// -------- mlp kernel: xo = LN1(x + mlp(h)) -------------------
__global__ __launch_bounds__(256, 4) void mlp_kernel(
    const float* __restrict__ x, float* __restrict__ xo,
    const unsigned short* __restrict__ h_bf,
    const unsigned short* __restrict__ W1b, const float* __restrict__ b1,
    const unsigned short* __restrict__ W2b, const float* __restrict__ b2,
    const float* __restrict__ g1, const float* __restrict__ bt1, int N) {
  __shared__ unsigned short a_s[128 * LDP];
  const int tid = threadIdx.x;
  const long long r0 = (long long)blockIdx.x * 128;

  for (int i = tid; i < 2048; i += 256) {
    int r = i >> 4, c = (i & 15) << 3;
    long long gr = r0 + r;
    bf16x8 v;
    if (gr < N) v = *(const bf16x8*)&h_bf[gr * HD + c];
    else {
#pragma unroll
      for (int k = 0; k < 8; ++k) v[k] = (__bf16)0.f;
    }
    *(bf16x8*)&a_s[r * LDP + c] = v;
  }
  __syncthreads();

  const int lane = tid & 63, w = tid >> 6;
  const int l15 = lane & 15, lg = lane >> 4;
  f32x4 acc[2][8];
#pragma unroll
  for (int mt = 0; mt < 2; ++mt)
#pragma unroll
    for (int nt = 0; nt < 8; ++nt) acc[mt][nt] = (f32x4){0.f, 0.f, 0.f, 0.f};
  mfma_tile_gb(a_s, W1b, 128, w, l15, lg, acc);
  __syncthreads();

#pragma unroll
  for (int mt = 0; mt < 2; ++mt)
#pragma unroll
    for (int r = 0; r < 4; ++r) {
      int m = w * 32 + mt * 16 + lg * 4 + r;
#pragma unroll
      for (int nt = 0; nt < 8; ++nt) {
        int n = nt * 16 + l15;
        float t = acc[mt][nt][r] + b1[n];
        a_s[m * LDP + n] = f2bf(t > 0.f ? t : 0.f);
      }
    }
  __syncthreads();

  f32x4 acc2[2][8];
#pragma unroll
  for (int mt = 0; mt < 2; ++mt)
#pragma unroll
    for (int nt = 0; nt < 8; ++nt) acc2[mt][nt] = (f32x4){0.f, 0.f, 0.f, 0.f};
  mfma_tile_gb(a_s, W2b, 128, w, l15, lg, acc2);
  __syncthreads();

#pragma unroll
  for (int mt = 0; mt < 2; ++mt)
#pragma unroll
    for (int r = 0; r < 4; ++r) {
      int m = w * 32 + mt * 16 + lg * 4 + r;
      if (r0 + m < N) {
#pragma unroll
        for (int nt = 0; nt < 8; ++nt) {
          int n = nt * 16 + l15;
          a_s[m * LDP + n] = f2bf(x[(r0 + m) * HD + n] + acc2[mt][nt][r] + b2[n]);
        }
      }
    }
  __syncthreads();

  for (int row = w; row < 128; row += 4) {
    if (r0 + row >= N) continue;
    float v1 = bf2f(a_s[row * LDP + lane]), v2 = bf2f(a_s[row * LDP + 64 + lane]);
    float s = v1 + v2, sq = v1 * v1 + v2 * v2;
    for (int o = 32; o > 0; o >>= 1) { s += __shfl_xor(s, o); sq += __shfl_xor(sq, o); }
    float mean = s * (1.f / 128.f);
    float var = sq * (1.f / 128.f) - mean * mean;
    float rs = rsqrtf(var + 1e-5f);
    xo[(r0 + row) * HD + lane]      = (v1 - mean) * rs * g1[lane] + bt1[lane];
    xo[(r0 + row) * HD + 64 + lane] = (v2 - mean) * rs * g1[lane + 64] + bt1[lane + 64];
  }
}

// ======== FUSED chem kernel: qkv -> 4-head attn -> oproj+LN2 -> ffn1 -> ffn2 ======
__global__ __launch_bounds__(256) void chem_kernel(
    float* __restrict__ xo,
    const unsigned short* __restrict__ inwb, const float* __restrict__ in_b,
    const unsigned short* __restrict__ wob, const float* __restrict__ bo,
    const float* __restrict__ g2, const float* __restrict__ bt2,
    const unsigned short* __restrict__ f1wb, const float* __restrict__ f1b,
    const unsigned short* __restrict__ f2wb, const float* __restrict__ f2b,
    const void* __restrict__ chem, const int* __restrict__ flag) {
  __shared__ unsigned short xc_s[128 * LDP];  // xc -> P -> h2
  __shared__ unsigned short q_s[128 * LDP];   // q  -> O -> u[0:128]
  __shared__ unsigned short k_s[128 * LDP];   // k  -> y stash (bf16)
  __shared__ unsigned short vt_s[128 * LDP];  // v^T -> u[128:256]
  __shared__ int s_row[128];
  const int tid = threadIdx.x, chunk = blockIdx.x;
  const int is64 = *flag;
  if (tid < 128) s_row[tid] = idx_at(chem, (long long)chunk * 128 + tid, is64);
  __syncthreads();

  for (int i = tid; i < 2048; i += 256) {
    int r = i >> 4, c = (i & 15) << 3;
    const float* src = &xo[(size_t)s_row[r] * HD + c];
    float4 f0 = *(const float4*)&src[0];
    float4 f1 = *(const float4*)&src[4];
    u16x4 h0 = { f2bf(f0.x), f2bf(f0.y), f2bf(f0.z), f2bf(f0.w) };
    u16x4 h1 = { f2bf(f1.x), f2bf(f1.y), f2bf(f1.z), f2bf(f1.w) };
    *(u16x4*)&xc_s[r * LDP + c] = h0;
    *(u16x4*)&xc_s[r * LDP + c + 4] = h1;
  }
  __syncthreads();

  const int lane = tid & 63, w = tid >> 6;
  const int l15 = lane & 15, lg = lane >> 4;
  const float scale = 0.1767766952966369f;

  for (int sec = 0; sec < 3; ++sec) {
    f32x4 acc[2][8];
#pragma unroll
    for (int mt = 0; mt < 2; ++mt)
#pragma unroll
      for (int nt = 0; nt < 8; ++nt) acc[mt][nt] = (f32x4){0.f, 0.f, 0.f, 0.f};
    mfma_tile_gb(xc_s, inwb + (size_t)sec * 128 * 128, 128, w, l15, lg, acc);
#pragma unroll
    for (int mt = 0; mt < 2; ++mt)
#pragma unroll
      for (int r = 0; r < 4; ++r) {
        int m = w * 32 + mt * 16 + lg * 4 + r;
#pragma unroll
        for (int nt = 0; nt < 8; ++nt) {
          int n = nt * 16 + l15;
          float t = acc[mt][nt][r] + in_b[sec * 128 + n];
          if (sec == 0)      q_s[m * LDP + n] = f2bf(t * scale);
          else if (sec == 1) k_s[m * LDP + n] = f2bf(t);
          else               vt_s[n * LDP + m] = f2bf(t);
        }
      }
  }
  __syncthreads();

  f32x4 oacc[2][8];
#pragma unroll
  for (int mt = 0; mt < 2; ++mt)
#pragma unroll
    for (int nt = 0; nt < 8; ++nt) oacc[mt][nt] = (f32x4){0.f, 0.f, 0.f, 0.f};

  for (int h = 0; h < 4; ++h) {
    f32x4 sacc[2][8];
#pragma unroll
    for (int mt = 0; mt < 2; ++mt)
#pragma unroll
      for (int nt = 0; nt < 8; ++nt) sacc[mt][nt] = (f32x4){0.f, 0.f, 0.f, 0.f};
    {
      bf16x8 a[2], b[8];
#pragma unroll
      for (int mt = 0; mt < 2; ++mt)
        a[mt] = *(const bf16x8*)&q_s[(w * 32 + mt * 16 + l15) * LDP + h * 32 + lg * 8];
#pragma unroll
      for (int nt = 0; nt < 8; ++nt)
        b[nt] = *(const bf16x8*)&k_s[(nt * 16 + l15) * LDP + h * 32 + lg * 8];
#pragma unroll
      for (int mt = 0; mt < 2; ++mt)
#pragma unroll
        for (int nt = 0; nt < 8; ++nt)
          sacc[mt][nt] = __builtin_amdgcn_mfma_f32_16x16x32_bf16(a[mt], b[nt], sacc[mt][nt], 0, 0, 0);
    }
#pragma unroll
    for (int mt = 0; mt < 2; ++mt)
#pragma unroll
      for (int r = 0; r < 4; ++r) {
        int m = w * 32 + mt * 16 + lg * 4 + r;
        float mx = -1e30f;
#pragma unroll
        for (int nt = 0; nt < 8; ++nt) mx = fmaxf(mx, sacc[mt][nt][r]);
        for (int o = 8; o > 0; o >>= 1) mx = fmaxf(mx, __shfl_xor(mx, o));
        float sm = 0.f;
        float p[8];
#pragma unroll
        for (int nt = 0; nt < 8; ++nt) { p[nt] = __expf(sacc[mt][nt][r] - mx); sm += p[nt]; }
        for (int o = 8; o > 0; o >>= 1) sm += __shfl_xor(sm, o);
        float inv = 1.f / sm;
#pragma unroll
        for (int nt = 0; nt < 8; ++nt)
          xc_s[m * LDP + nt * 16 + l15] = f2bf(p[nt] * inv);
      }
#pragma unroll
    for (int kk = 0; kk < 4; ++kk) {
      bf16x8 pa[2], vb[2];
#pragma unroll
      for (int mt = 0; mt < 2; ++mt)
        pa[mt] = *(const bf16x8*)&xc_s[(w * 32 + mt * 16 + l15) * LDP + kk * 32 + lg * 8];
#pragma unroll
      for (int nt2 = 0; nt2 < 2; ++nt2)
        vb[nt2] = *(const bf16x8*)&vt_s[(h * 32 + nt2 * 16 + l15) * LDP + kk * 32 + lg * 8];
#pragma unroll
      for (int mt = 0; mt < 2; ++mt)
#pragma unroll
        for (int nt2 = 0; nt2 < 2; ++nt2)
          oacc[mt][h * 2 + nt2] =
              __builtin_amdgcn_mfma_f32_16x16x32_bf16(pa[mt], vb[nt2], oacc[mt][h * 2 + nt2], 0, 0, 0);
    }
  }
  __syncthreads();

#pragma unroll
  for (int mt = 0; mt < 2; ++mt)
#pragma unroll
    for (int r = 0; r < 4; ++r) {
      int m = w * 32 + mt * 16 + lg * 4 + r;
#pragma unroll
      for (int nt = 0; nt < 8; ++nt)
        q_s[m * LDP + nt * 16 + l15] = f2bf(oacc[mt][nt][r]);
    }

  f32x4 pacc[2][8];
#pragma unroll
  for (int mt = 0; mt < 2; ++mt)
#pragma unroll
    for (int nt = 0; nt < 8; ++nt) pacc[mt][nt] = (f32x4){0.f, 0.f, 0.f, 0.f};
  mfma_tile_gb(q_s, wob, 128, w, l15, lg, pacc);

#pragma unroll
  for (int mt = 0; mt < 2; ++mt)
#pragma unroll
    for (int r = 0; r < 4; ++r) {
      int m = w * 32 + mt * 16 + lg * 4 + r;
      const float* xrow = &xo[(size_t)s_row[m] * HD];
      float y[8];
      float s = 0.f, sq = 0.f;
#pragma unroll
      for (int nt = 0; nt < 8; ++nt) {
        int n = nt * 16 + l15;
        y[nt] = xrow[n] + pacc[mt][nt][r] + bo[n];
        s += y[nt]; sq += y[nt] * y[nt];
      }
      for (int o = 8; o > 0; o >>= 1) { s += __shfl_xor(s, o); sq += __shfl_xor(sq, o); }
      float mean = s * (1.f / 128.f);
      float var = sq * (1.f / 128.f) - mean * mean;
      float rs = rsqrtf(var + 1e-5f);
#pragma unroll
      for (int nt = 0; nt < 8; ++nt) {
        int n = nt * 16 + l15;
        xc_s[m * LDP + n] = f2bf((y[nt] - mean) * rs * g2[n] + bt2[n]);
        k_s[m * LDP + n]  = f2bf(y[nt]);
      }
    }

  for (int sec = 0; sec < 2; ++sec) {
    f32x4 acc[2][8];
#pragma unroll
    for (int mt = 0; mt < 2; ++mt)
#pragma unroll
      for (int nt = 0; nt < 8; ++nt) acc[mt][nt] = (f32x4){0.f, 0.f, 0.f, 0.f};
    mfma_tile_gb(xc_s, f1wb + (size_t)sec * 128 * 128, 128, w, l15, lg, acc);
    unsigned short* ub = (sec == 0) ? q_s : vt_s;
#pragma unroll
    for (int mt = 0; mt < 2; ++mt)
#pragma unroll
      for (int r = 0; r < 4; ++r) {
        int m = w * 32 + mt * 16 + lg * 4 + r;
#pragma unroll
        for (int nt = 0; nt < 8; ++nt) {
          int n = nt * 16 + l15;
          float t = acc[mt][nt][r] + f1b[sec * 128 + n];
          ub[m * LDP + n] = f2bf(t > 0.f ? t : 0.f);
        }
      }
  }

  f32x4 facc[2][8];
#pragma unroll
  for (int mt = 0; mt < 2; ++mt)
#pragma unroll
    for (int nt = 0; nt < 8; ++nt) facc[mt][nt] = (f32x4){0.f, 0.f, 0.f, 0.f};
  mfma_tile_gb(q_s, f2wb, 256, w, l15, lg, facc);
  mfma_tile_gb(vt_s, f2wb + 128, 256, w, l15, lg, facc);

#pragma unroll
  for (int mt = 0; mt < 2; ++mt)
#pragma unroll
    for (int r = 0; r < 4; ++r) {
      int m = w * 32 + mt * 16 + lg * 4 + r;
      float* orow = &xo[(size_t)s_row[m] * HD];
#pragma unroll
      for (int nt = 0; nt < 8; ++nt) {
        int n = nt * 16 + l15;
        orow[n] = bf2f(k_s[m * LDP + n]) + facc[mt][nt][r] + f2b[n];
      }
    }
}

// ================= FALLBACK (small ws): atomic edge + fused node =================
__global__ __launch_bounds__(256) void edge_kernel(
    const float* __restrict__ x, const float* __restrict__ ea,
    const float* __restrict__ We, const float* __restrict__ be,
    const void* __restrict__ ei, const int* __restrict__ flag,
    float* __restrict__ agg, int E, int N) {
  __shared__ unsigned short ea_s[128 * LDP];
  __shared__ unsigned short we_s[128 * LDP];
  __shared__ int s_src[128];
  __shared__ int s_dst[128];
  const int tid = threadIdx.x;
  const long long e0 = (long long)blockIdx.x * 128;
  const int is64 = *flag;
  if (tid < 128) {
    long long e = e0 + tid;
    int s = 0, d = 0;
    if (e < E) { s = idx_at(ei, e, is64); d = idx_at(ei, (long long)E + e, is64); }
    s_src[tid] = s; s_dst[tid] = d;
  }
  for (int i = tid; i < 128 * 32; i += 256) {
    int r = i >> 5, c = (i & 31) << 2;
    float4 f = {0.f, 0.f, 0.f, 0.f};
    if (e0 + r < E) f = *(const float4*)&ea[(e0 + r) * HD + c];
    u16x4 h = { f2bf(f.x), f2bf(f.y), f2bf(f.z), f2bf(f.w) };
    *(u16x4*)&ea_s[r * LDP + c] = h;
    float4 g = *(const float4*)&We[r * HD + c];
    u16x4 hw = { f2bf(g.x), f2bf(g.y), f2bf(g.z), f2bf(g.w) };
    *(u16x4*)&we_s[r * LDP + c] = hw;
  }
  __syncthreads();
  const int lane = tid & 63, w = tid >> 6;
  const int l15 = lane & 15, lg = lane >> 4;
  f32x4 acc[2][8];
#pragma unroll
  for (int mt = 0; mt < 2; ++mt)
#pragma unroll
    for (int nt = 0; nt < 8; ++nt) acc[mt][nt] = (f32x4){0.f, 0.f, 0.f, 0.f};
  mfma_tile_128(ea_s, we_s, w, l15, lg, acc);
  float bev[8];
#pragma unroll
  for (int nt = 0; nt < 8; ++nt) bev[nt] = be[nt * 16 + l15];
#pragma unroll
  for (int mt = 0; mt < 2; ++mt) {
#pragma unroll
    for (int r = 0; r < 4; ++r) {
      int m = w * 32 + mt * 16 + lg * 4 + r;
      if (e0 + m >= E) continue;
      const float* xrow = x + (size_t)s_src[m] * HD;
      float* arow = agg + (size_t)s_dst[m] * HD;
#pragma unroll
      for (int nt = 0; nt < 8; ++nt) {
        int n = nt * 16 + l15;
        float val = acc[mt][nt][r] + bev[nt] + xrow[n];
        if (val > 0.f) unsafeAtomicAdd(&arow[n], val);
      }
    }
  }
}

__global__ __launch_bounds__(256) void node_kernel(
    const float* __restrict__ x, float* xo,
    const float* __restrict__ W1, const float* __restrict__ b1,
    const float* __restrict__ W2, const float* __restrict__ b2,
    const float* __restrict__ g1, const float* __restrict__ bt1, int N) {
  __shared__ char smem[2 * 128 * LDP * 2];
  unsigned short* a_s = (unsigned short*)smem;
  unsigned short* w_s = (unsigned short*)smem + 128 * LDP;
  float* y_s = (float*)smem;
  const int tid = threadIdx.x;
  const long long r0 = (long long)blockIdx.x * 128;
  for (int i = tid; i < 128 * 32; i += 256) {
    int r = i >> 5, c = (i & 31) << 2;
    float4 f = {0.f, 0.f, 0.f, 0.f};
    if (r0 + r < N) {
      float4 xa = *(const float4*)&x[(r0 + r) * HD + c];
      float4 ag = *(const float4*)&xo[(r0 + r) * HD + c];
      f.x = xa.x + ag.x; f.y = xa.y + ag.y; f.z = xa.z + ag.z; f.w = xa.w + ag.w;
    }
    u16x4 h = { f2bf(f.x), f2bf(f.y), f2bf(f.z), f2bf(f.w) };
    *(u16x4*)&a_s[r * LDP + c] = h;
    float4 g = *(const float4*)&W1[r * HD + c];
    u16x4 hw = { f2bf(g.x), f2bf(g.y), f2bf(g.z), f2bf(g.w) };
    *(u16x4*)&w_s[r * LDP + c] = hw;
  }
  __syncthreads();
  const int lane = tid & 63, w = tid >> 6;
  const int l15 = lane & 15, lg = lane >> 4;
  f32x4 acc[2][8];
#pragma unroll
  for (int mt = 0; mt < 2; ++mt)
#pragma unroll
    for (int nt = 0; nt < 8; ++nt) acc[mt][nt] = (f32x4){0.f, 0.f, 0.f, 0.f};
  mfma_tile_128(a_s, w_s, w, l15, lg, acc);
  __syncthreads();
#pragma unroll
  for (int mt = 0; mt < 2; ++mt)
#pragma unroll
    for (int r = 0; r < 4; ++r) {
      int m = w * 32 + mt * 16 + lg * 4 + r;
#pragma unroll
      for (int nt = 0; nt < 8; ++nt) {
        int n = nt * 16 + l15;
        float t = acc[mt][nt][r] + b1[n];
        a_s[m * LDP + n] = f2bf(t > 0.f ? t : 0.f);
      }
    }
  stage_f32s(w_s, W2, HD, tid, 256);
  __syncthreads();
  f32x4 acc2[2][8];
#pragma unroll
  for (int mt = 0; mt < 2; ++mt)
#pragma unroll
    for (int nt = 0; nt < 8; ++nt) acc2[mt][nt] = (f32x4){0.f, 0.f, 0.f, 0.f};
  mfma_tile_128(a_s, w_s, w, l15, lg, acc2);
  __syncthreads();
#pragma unroll
  for (int mt = 0; mt < 2; ++mt)
#pragma unroll
    for (int r = 0; r < 4; ++r) {
      int m = w * 32 + mt * 16 + lg * 4 + r;
      if (r0 + m < N) {
#pragma unroll
        for (int nt = 0; nt < 8; ++nt) {
          int n = nt * 16 + l15;
          y_s[m * 132 + n] = x[(r0 + m) * HD + n] + acc2[mt][nt][r] + b2[n];
        }
      }
    }
  __syncthreads();
  for (int row = w; row < 128; row += 4) {
    if (r0 + row >= N) continue;
    float v1 = y_s[row * 132 + lane], v2 = y_s[row * 132 + 64 + lane];
    float s = v1 + v2, sq = v1 * v1 + v2 * v2;
    for (int o = 32; o > 0; o >>= 1) { s += __shfl_xor(s, o); sq += __shfl_xor(sq, o); }
    float mean = s * (1.f / 128.f);
    float var = sq * (1.f / 128.f) - mean * mean;
    float rs = rsqrtf(var + 1e-5f);
    xo[(r0 + row) * HD + lane]      = (v1 - mean) * rs * g1[lane] + bt1[lane];
    xo[(r0 + row) * HD + 64 + lane] = (v2 - mean) * rs * g1[lane + 64] + bt1[lane + 64];
  }
}

extern "C" void kernel_launch(void* const* d_in, const int* in_sizes, int n_in,
                              void* d_out, int out_size, void* d_ws, size_t ws_size,
                              hipStream_t stream) {
  const float* x    = (const float*)d_in[0];
  const float* ea   = (const float*)d_in[1];
  const float* We   = (const float*)d_in[2];
  const float* be   = (const float*)d_in[3];
  const float* W1   = (const float*)d_in[4];
  const float* b1   = (const float*)d_in[5];
  const float* W2   = (const float*)d_in[6];
  const float* b2   = (const float*)d_in[7];
  const float* g1   = (const float*)d_in[8];
  const float* bt1  = (const float*)d_in[9];
  const float* in_w = (const float*)d_in[10];
  const float* in_b = (const float*)d_in[11];
  const float* outw = (const float*)d_in[12];
  const float* outb = (const float*)d_in[13];
  const float* g2   = (const float*)d_in[14];
  const float* bt2  = (const float*)d_in[15];
  const float* f1w  = (const float*)d_in[16];
  const float* f1b  = (const float*)d_in[17];
  const float* f2w  = (const float*)d_in[18];
  const float* f2b  = (const float*)d_in[19];
  const void*  ei   = d_in[20];
  const void*  chem = d_in[21];
  const int N  = in_sizes[0] / HD;
  const int E  = in_sizes[1] / HD;
  const int NC = in_sizes[21];
  const int NB = (N + SCH - 1) / SCH;
  float* xo = (float*)d_out;

  char* ws = (char*)d_ws;
  size_t o = 0;
  auto alloc = [&](size_t bytes) { size_t p = o; o = (o + bytes + 255) & ~255ULL; return p; };
  size_t o_flag = alloc(4);
  size_t o_webf = alloc(128 * 128 * 2);
  size_t o_w1b  = alloc(128 * 128 * 2);
  size_t o_w2b  = alloc(128 * 128 * 2);
  size_t o_inwb = alloc(384 * 128 * 2);
  size_t o_wob  = alloc(128 * 128 * 2);
  size_t o_f1wb = alloc(256 * 128 * 2);
  size_t o_f2wb = alloc(128 * 256 * 2);
  size_t o_xbf  = alloc((size_t)N * 128 * 2);
  size_t o_hbf  = alloc((size_t)N * 128 * 2);
  size_t o_deg  = alloc((size_t)N * 4);
  size_t o_off  = alloc((size_t)(N + 1) * 4);
  size_t o_cur  = alloc((size_t)N * 4);
  size_t o_bsum = alloc((size_t)NB * 4);
  size_t o_msg  = alloc((size_t)E * 128 * 2);
  size_t need = o;

  int*            flag = (int*)(ws + o_flag);
  unsigned short* webf = (unsigned short*)(ws + o_webf);
  unsigned short* w1b  = (unsigned short*)(ws + o_w1b);
  unsigned short* w2b  = (unsigned short*)(ws + o_w2b);
  unsigned short* inwb = (unsigned short*)(ws + o_inwb);
  unsigned short* wob  = (unsigned short*)(ws + o_wob);
  unsigned short* f1wb = (unsigned short*)(ws + o_f1wb);
  unsigned short* f2wb = (unsigned short*)(ws + o_f2wb);
  unsigned short* xbf  = (unsigned short*)(ws + o_xbf);
  unsigned short* hbf  = (unsigned short*)(ws + o_hbf);
  int*            deg  = (int*)(ws + o_deg);
  int*            off  = (int*)(ws + o_off);
  int*            cur  = (int*)(ws + o_cur);
  int*            bsum = (int*)(ws + o_bsum);
  unsigned short* msg  = (unsigned short*)(ws + o_msg);

  detect_idx_kernel<<<1, 64, 0, stream>>>(ei, E, N, flag);
  conv_weights_kernel<<<dim3(640), 256, 0, stream>>>(W1, W2, in_w, outw, f1w, f2w,
                                                     w1b, w2b, inwb, wob, f1wb, f2wb);

  if (ws_size >= need) {
    hipMemsetAsync(deg, 0, (size_t)N * 4, stream);
    conv_x_kernel<<<dim3((N * 16 + 255) / 256), 256, 0, stream>>>(x, xbf, (long long)N * 16);
    hist_kernel<<<dim3(1024), 256, 0, stream>>>(ei, flag, deg, E);
    scan_a<<<dim3(NB), 256, 0, stream>>>(deg, bsum, N);
    if (NB <= 128) scan_b2<<<1, 128, 0, stream>>>(bsum, off, NB, N);
    else           scan_b<<<1, 64, 0, stream>>>(bsum, off, NB, N);
    scan_c<<<dim3(NB), 256, 0, stream>>>(deg, bsum, off, cur, N);
    conv_we_kernel<<<dim3(64), 256, 0, stream>>>(We, webf);
    edge_kernel13<<<dim3((E + 127) / 128), 256, 0, stream>>>(xbf, ea, webf, be, ei,
                                                             flag, cur, msg, E);
    gather_kernel<<<dim3((N + 15) / 16), 256, 0, stream>>>(xbf, off, msg, hbf, N);
    mlp_kernel<<<dim3((N + 127) / 128), 256, 0, stream>>>(x, xo, hbf, w1b, b1, w2b,
                                                          b2, g1, bt1, N);
  } else {
    hipMemsetAsync(xo, 0, (size_t)N * HD * sizeof(float), stream);
    edge_kernel<<<dim3((E + 127) / 128), 256, 0, stream>>>(x, ea, We, be, ei, flag, xo, E, N);
    node_kernel<<<dim3((N + 127) / 128), 256, 0, stream>>>(x, xo, W1, b1, W2, b2, g1, bt1, N);
  }

  chem_kernel<<<dim3(NC / 128), 256, 0, stream>>>(xo, inwb, in_b, wob, outb, g2, bt2,
                                                  f1wb, f1b, f2wb, f2b, chem, flag);
}

// Round 14
// 657.294 us; speedup vs baseline: 1.2009x; 1.0996x over previous
//
#include <hip/hip_runtime.h>
#include <hip/hip_bf16.h>
#include <math.h>

typedef __attribute__((ext_vector_type(8))) __bf16 bf16x8;
typedef __attribute__((ext_vector_type(4))) float f32x4;
typedef __attribute__((ext_vector_type(4))) unsigned short u16x4;

#define HD  128
#define LDP 136

__device__ __forceinline__ unsigned short f2bf(float f) {
  __bf16 h = (__bf16)f;
  union { __bf16 h; unsigned short u; } v; v.h = h; return v.u;
}
__device__ __forceinline__ float bf2f(unsigned short h) {
  union { unsigned u; float f; } v; v.u = ((unsigned)h) << 16; return v.f;
}

__device__ __forceinline__ int idx_at(const void* p, long long i, int is64) {
  if (is64) return (int)((const long long*)p)[i];
  return ((const int*)p)[i];
}

// 128x128 += A(LDS bf16 LDP) @ B^T(LDS bf16 LDP). wave w: rows [w*32,w*32+32)
// D: m = w*32+mt*16+(lane>>4)*4+r, n = nt*16+(lane&15)
__device__ __forceinline__ void mfma_tile_128(const unsigned short* a_s,
                                              const unsigned short* w_s,
                                              int w, int l15, int lg,
                                              f32x4 acc[2][8]) {
#pragma unroll
  for (int kk = 0; kk < 4; ++kk) {
    bf16x8 a[2], b[8];
#pragma unroll
    for (int mt = 0; mt < 2; ++mt)
      a[mt] = *(const bf16x8*)&a_s[(w * 32 + mt * 16 + l15) * LDP + kk * 32 + lg * 8];
#pragma unroll
    for (int nt = 0; nt < 8; ++nt)
      b[nt] = *(const bf16x8*)&w_s[(nt * 16 + l15) * LDP + kk * 32 + lg * 8];
#pragma unroll
    for (int mt = 0; mt < 2; ++mt)
#pragma unroll
      for (int nt = 0; nt < 8; ++nt)
        acc[mt][nt] = __builtin_amdgcn_mfma_f32_16x16x32_bf16(a[mt], b[nt], acc[mt][nt], 0, 0, 0);
  }
}

// B fragments from GLOBAL bf16 [128][ldw] (L2-hot weights)
__device__ __forceinline__ void mfma_tile_gb(const unsigned short* a_s,
                                             const unsigned short* Wb, int ldw,
                                             int w, int l15, int lg,
                                             f32x4 acc[2][8]) {
#pragma unroll
  for (int kk = 0; kk < 4; ++kk) {
    bf16x8 a[2], b[8];
#pragma unroll
    for (int mt = 0; mt < 2; ++mt)
      a[mt] = *(const bf16x8*)&a_s[(w * 32 + mt * 16 + l15) * LDP + kk * 32 + lg * 8];
#pragma unroll
    for (int nt = 0; nt < 8; ++nt)
      b[nt] = *(const bf16x8*)&Wb[(size_t)(nt * 16 + l15) * ldw + kk * 32 + lg * 8];
#pragma unroll
    for (int mt = 0; mt < 2; ++mt)
#pragma unroll
      for (int nt = 0; nt < 8; ++nt)
        acc[mt][nt] = __builtin_amdgcn_mfma_f32_16x16x32_bf16(a[mt], b[nt], acc[mt][nt], 0, 0, 0);
  }
}

__device__ __forceinline__ void stage_f32s(unsigned short* dst, const float* src,
                                           long long src_ld, int tid, int T) {
  for (int i = tid; i < 128 * 32; i += T) {
    int r = i >> 5, c = (i & 31) << 2;
    float4 f = *(const float4*)&src[(long long)r * src_ld + c];
    u16x4 h = { f2bf(f.x), f2bf(f.y), f2bf(f.z), f2bf(f.w) };
    *(u16x4*)&dst[r * LDP + c] = h;
  }
}

// ---------------- index dtype detector ----------------
__global__ void detect_idx_kernel(const void* __restrict__ ei, int E, int N,
                                  int* __restrict__ flag) {
  if (threadIdx.x == 0 && blockIdx.x == 0) {
    const long long* p = (const long long*)ei;
    int is64 = 1;
    long long step = E / 64; if (step < 1) step = 1;
    for (int i = 0; i < 64; ++i) {
      long long v = p[i * step];
      if (v < 0 || v >= N) { is64 = 0; break; }
    }
    *flag = is64;
  }
}

// ---------------- f32 -> bf16 pre-converts ----------------
__global__ __launch_bounds__(256) void conv_we_kernel(const float* __restrict__ We,
                                                      unsigned short* __restrict__ we_bf) {
  int i = blockIdx.x * 256 + threadIdx.x;
  if (i < 128 * 128) we_bf[i] = f2bf(We[i]);
}
__global__ __launch_bounds__(256) void conv_weights_kernel(
    const float* __restrict__ W1, const float* __restrict__ W2,
    const float* __restrict__ inw, const float* __restrict__ wo,
    const float* __restrict__ f1, const float* __restrict__ f2,
    unsigned short* __restrict__ w1b, unsigned short* __restrict__ w2b,
    unsigned short* __restrict__ inwb, unsigned short* __restrict__ wob,
    unsigned short* __restrict__ f1b, unsigned short* __restrict__ f2b) {
  int i = blockIdx.x * 256 + threadIdx.x;
  if (i < 16384) w1b[i] = f2bf(W1[i]);
  else if (i < 32768) w2b[i - 16384] = f2bf(W2[i - 16384]);
  else if (i < 81920) inwb[i - 32768] = f2bf(inw[i - 32768]);
  else if (i < 98304) wob[i - 81920] = f2bf(wo[i - 81920]);
  else if (i < 131072) f1b[i - 98304] = f2bf(f1[i - 98304]);
  else if (i < 163840) f2b[i - 131072] = f2bf(f2[i - 131072]);
}
__global__ __launch_bounds__(256) void conv_x_kernel(const float* __restrict__ x,
                                                     unsigned short* __restrict__ xb,
                                                     long long n8) {
  long long i = blockIdx.x * 256LL + threadIdx.x;
  if (i < n8) {
    float4 f0 = *(const float4*)&x[i * 8];
    float4 f1 = *(const float4*)&x[i * 8 + 4];
    u16x4 h0 = { f2bf(f0.x), f2bf(f0.y), f2bf(f0.z), f2bf(f0.w) };
    u16x4 h1 = { f2bf(f1.x), f2bf(f1.y), f2bf(f1.z), f2bf(f1.w) };
    *(u16x4*)&xb[i * 8] = h0;
    *(u16x4*)&xb[i * 8 + 4] = h1;
  }
}

// ---------------- dst histogram ----------------
__global__ __launch_bounds__(256) void hist_kernel(const void* __restrict__ ei,
                                                   const int* __restrict__ flag,
                                                   int* __restrict__ deg, int E) {
  const int is64 = *flag;
  for (long long e = blockIdx.x * 256LL + threadIdx.x; e < E;
       e += (long long)gridDim.x * 256)
    atomicAdd(&deg[idx_at(ei, (long long)E + e, is64)], 1);
}

// ---------------- 3-phase exclusive scan ----------------
#define SCH 1024
__global__ __launch_bounds__(256) void scan_a(const int* __restrict__ deg,
                                              int* __restrict__ bsum, int N) {
  const int b = blockIdx.x, t = threadIdx.x;
  int p = 0;
#pragma unroll
  for (int k = 0; k < 4; ++k) {
    int idx = b * SCH + t * 4 + k;
    if (idx < N) p += deg[idx];
  }
  __shared__ int warr[4];
  for (int o = 32; o > 0; o >>= 1) p += __shfl_xor(p, o);
  if ((t & 63) == 0) warr[t >> 6] = p;
  __syncthreads();
  if (t == 0) bsum[b] = warr[0] + warr[1] + warr[2] + warr[3];
}
__global__ void scan_b(int* __restrict__ bsum, int* __restrict__ off, int NB, int N) {
  if (threadIdx.x == 0 && blockIdx.x == 0) {
    int run = 0;
    for (int b = 0; b < NB; ++b) { int t = bsum[b]; bsum[b] = run; run += t; }
    off[N] = run;
  }
}
__global__ __launch_bounds__(128) void scan_b2(int* __restrict__ bsum,
                                               int* __restrict__ off, int NB, int N) {
  __shared__ int arr[128];
  const int t = threadIdx.x;
  int v = (t < NB) ? bsum[t] : 0;
  arr[t] = v;
  __syncthreads();
  for (int s = 1; s < 128; s <<= 1) {
    int u = (t >= s) ? arr[t - s] : 0;
    __syncthreads();
    arr[t] += u;
    __syncthreads();
  }
  if (t < NB) bsum[t] = arr[t] - v;
  if (t == 0) off[N] = arr[127];
}
__global__ __launch_bounds__(256) void scan_c(const int* __restrict__ deg,
                                              const int* __restrict__ bsum,
                                              int* __restrict__ off,
                                              int* __restrict__ cursor, int N) {
  const int b = blockIdx.x, t = threadIdx.x;
  int d[4], s = 0;
#pragma unroll
  for (int k = 0; k < 4; ++k) {
    int idx = b * SCH + t * 4 + k;
    d[k] = (idx < N) ? deg[idx] : 0;
    s += d[k];
  }
  __shared__ int arr[256];
  arr[t] = s;
  __syncthreads();
  for (int stp = 1; stp < 256; stp <<= 1) {
    int v = (t >= stp) ? arr[t - stp] : 0;
    __syncthreads();
    arr[t] += v;
    __syncthreads();
  }
  int base = bsum[b] + arr[t] - s;
  int acc = 0;
#pragma unroll
  for (int k = 0; k < 4; ++k) {
    int idx = b * SCH + t * 4 + k;
    if (idx < N) { off[idx] = base + acc; cursor[idx] = base + acc; }
    acc += d[k];
  }
}

// -------- edge kernel (r11 winner): streaming A->regs, We in LDS, CSR msg writes ---
__global__ __launch_bounds__(256, 4) void edge_kernel11(
    const unsigned short* __restrict__ x_bf, const float* __restrict__ ea,
    const unsigned short* __restrict__ we_bf, const float* __restrict__ be,
    const void* __restrict__ ei, const int* __restrict__ flag,
    int* __restrict__ cursor, unsigned short* __restrict__ msg, int E) {
  __shared__ unsigned short we_s[128 * LDP];   // We tile; reused as gemm-out staging
  __shared__ int s_src[128];
  __shared__ int s_pos[128];
  const int tid = threadIdx.x;
  const long long e0 = (long long)blockIdx.x * 128;
  const int is64 = *flag;

  if (tid < 128) {
    long long e = e0 + tid;
    int s = 0, p = 0;
    if (e < E) {
      s = idx_at(ei, e, is64);
      int d = idx_at(ei, (long long)E + e, is64);
      p = atomicAdd(&cursor[d], 1);
    }
    s_src[tid] = s; s_pos[tid] = p;
  }

  const int lane = tid & 63, w = tid >> 6;
  const int l15 = lane & 15, lg = lane >> 4;

  // A fragments from global (streaming, edge order)
  float4 af[2][4][2];
#pragma unroll
  for (int mt = 0; mt < 2; ++mt) {
    long long row = e0 + w * 32 + mt * 16 + l15;
    const float* src = &ea[(row < E ? row : e0) * HD + lg * 8];
#pragma unroll
    for (int kk = 0; kk < 4; ++kk) {
      af[mt][kk][0] = *(const float4*)&src[kk * 32];
      af[mt][kk][1] = *(const float4*)&src[kk * 32 + 4];
    }
  }

  // stage bf16 We [128][128] -> LDS (pure 16B copies)
  for (int i = tid; i < 2048; i += 256) {
    int r = i >> 4, c = (i & 15) << 3;
    *(float4*)&we_s[r * LDP + c] = *(const float4*)&we_bf[r * 128 + c];
  }

  bf16x8 a[2][4];
#pragma unroll
  for (int mt = 0; mt < 2; ++mt)
#pragma unroll
    for (int kk = 0; kk < 4; ++kk) {
      float4 f0 = af[mt][kk][0], f1 = af[mt][kk][1];
      bf16x8 t;
      t[0] = (__bf16)f0.x; t[1] = (__bf16)f0.y; t[2] = (__bf16)f0.z; t[3] = (__bf16)f0.w;
      t[4] = (__bf16)f1.x; t[5] = (__bf16)f1.y; t[6] = (__bf16)f1.z; t[7] = (__bf16)f1.w;
      a[mt][kk] = t;
    }
  __syncthreads();

  f32x4 acc[2][8];
#pragma unroll
  for (int mt = 0; mt < 2; ++mt)
#pragma unroll
    for (int nt = 0; nt < 8; ++nt) acc[mt][nt] = (f32x4){0.f, 0.f, 0.f, 0.f};
#pragma unroll
  for (int kk = 0; kk < 4; ++kk) {
    bf16x8 b[8];
#pragma unroll
    for (int nt = 0; nt < 8; ++nt)
      b[nt] = *(const bf16x8*)&we_s[(nt * 16 + l15) * LDP + kk * 32 + lg * 8];
#pragma unroll
    for (int mt = 0; mt < 2; ++mt)
#pragma unroll
      for (int nt = 0; nt < 8; ++nt)
        acc[mt][nt] = __builtin_amdgcn_mfma_f32_16x16x32_bf16(a[mt][kk], b[nt], acc[mt][nt], 0, 0, 0);
  }

  float bev[8];
#pragma unroll
  for (int nt = 0; nt < 8; ++nt) bev[nt] = be[nt * 16 + l15];
  __syncthreads();   // all We reads done -> reuse we_s as gemm-out staging

  // epilogue 1: (gemm + be) -> LDS bf16 (own rows)
#pragma unroll
  for (int mt = 0; mt < 2; ++mt)
#pragma unroll
    for (int r = 0; r < 4; ++r) {
      int m = w * 32 + mt * 16 + lg * 4 + r;
#pragma unroll
      for (int nt = 0; nt < 8; ++nt)
        we_s[m * LDP + nt * 16 + l15] = f2bf(acc[mt][nt][r] + bev[nt]);
    }
  __syncthreads();

  // epilogue 2: bf16 x-row add + relu + CSR msg write (256B/row)
  for (int i = tid; i < 128 * 16; i += 256) {
    int r = i >> 4, sg = i & 15;
    if (e0 + r >= E) continue;
    bf16x8 xv = *(const bf16x8*)&x_bf[(size_t)s_src[r] * HD + sg * 8];
    bf16x8 g = *(const bf16x8*)&we_s[r * LDP + sg * 8];
    u16x4 h0, h1;
#pragma unroll
    for (int k = 0; k < 4; ++k) {
      float v = (float)g[k] + (float)xv[k];
      h0[k] = f2bf(v > 0.f ? v : 0.f);
    }
#pragma unroll
    for (int k = 0; k < 4; ++k) {
      float v = (float)g[4 + k] + (float)xv[4 + k];
      h1[k] = f2bf(v > 0.f ? v : 0.f);
    }
    unsigned short* mp = &msg[(size_t)s_pos[r] * 128 + sg * 8];
    *(u16x4*)&mp[0] = h0;
    *(u16x4*)&mp[4] = h1;
  }
}

// -------- gather kernel: sequential segment reads, unroll-8 -------------
__global__ __launch_bounds__(256) void gather_kernel(
    const unsigned short* __restrict__ x_bf, const int* __restrict__ off,
    const unsigned short* __restrict__ msg, unsigned short* __restrict__ h_bf,
    int N) {
  const int tid = threadIdx.x;
  const int grp = tid >> 4, li = tid & 15;
  const long long row = (long long)blockIdx.x * 16 + grp;
  if (row >= N) return;
  const int co = li * 8;
  float a8[8];
  bf16x8 xv = *(const bf16x8*)&x_bf[row * HD + co];
#pragma unroll
  for (int k = 0; k < 8; ++k) a8[k] = (float)xv[k];
  const int j0 = off[row], j1 = off[row + 1];
  int j = j0;
  for (; j + 7 < j1; j += 8) {
    bf16x8 v[8];
#pragma unroll
    for (int q = 0; q < 8; ++q)
      v[q] = *(const bf16x8*)&msg[(size_t)(j + q) * 128 + co];
#pragma unroll
    for (int k = 0; k < 8; ++k)
      a8[k] += (((float)v[0][k] + (float)v[1][k]) + ((float)v[2][k] + (float)v[3][k])) +
               (((float)v[4][k] + (float)v[5][k]) + ((float)v[6][k] + (float)v[7][k]));
  }
  for (; j < j1; ++j) {
    bf16x8 v0 = *(const bf16x8*)&msg[(size_t)j * 128 + co];
#pragma unroll
    for (int k = 0; k < 8; ++k) a8[k] += (float)v0[k];
  }
  bf16x8 hv;
#pragma unroll
  for (int k = 0; k < 8; ++k) hv[k] = (__bf16)a8[k];
  *(bf16x8*)&h_bf[row * HD + co] = hv;
}

// -------- mlp kernel: xo = LN1(x + mlp(h)) -------------------
__global__ __launch_bounds__(256, 4) void mlp_kernel(
    const float* __restrict__ x, float* __restrict__ xo,
    const unsigned short* __restrict__ h_bf,
    const unsigned short* __restrict__ W1b, const float* __restrict__ b1,
    const unsigned short* __restrict__ W2b, const float* __restrict__ b2,
    const float* __restrict__ g1, const float* __restrict__ bt1, int N) {
  __shared__ unsigned short a_s[128 * LDP];
  const int tid = threadIdx.x;
  const long long r0 = (long long)blockIdx.x * 128;

  for (int i = tid; i < 2048; i += 256) {
    int r = i >> 4, c = (i & 15) << 3;
    long long gr = r0 + r;
    bf16x8 v;
    if (gr < N) v = *(const bf16x8*)&h_bf[gr * HD + c];
    else {
#pragma unroll
      for (int k = 0; k < 8; ++k) v[k] = (__bf16)0.f;
    }
    *(bf16x8*)&a_s[r * LDP + c] = v;
  }
  __syncthreads();

  const int lane = tid & 63, w = tid >> 6;
  const int l15 = lane & 15, lg = lane >> 4;
  f32x4 acc[2][8];
#pragma unroll
  for (int mt = 0; mt < 2; ++mt)
#pragma unroll
    for (int nt = 0; nt < 8; ++nt) acc[mt][nt] = (f32x4){0.f, 0.f, 0.f, 0.f};
  mfma_tile_gb(a_s, W1b, 128, w, l15, lg, acc);
  __syncthreads();

#pragma unroll
  for (int mt = 0; mt < 2; ++mt)
#pragma unroll
    for (int r = 0; r < 4; ++r) {
      int m = w * 32 + mt * 16 + lg * 4 + r;
#pragma unroll
      for (int nt = 0; nt < 8; ++nt) {
        int n = nt * 16 + l15;
        float t = acc[mt][nt][r] + b1[n];
        a_s[m * LDP + n] = f2bf(t > 0.f ? t : 0.f);
      }
    }
  __syncthreads();

  f32x4 acc2[2][8];
#pragma unroll
  for (int mt = 0; mt < 2; ++mt)
#pragma unroll
    for (int nt = 0; nt < 8; ++nt) acc2[mt][nt] = (f32x4){0.f, 0.f, 0.f, 0.f};
  mfma_tile_gb(a_s, W2b, 128, w, l15, lg, acc2);
  __syncthreads();

#pragma unroll
  for (int mt = 0; mt < 2; ++mt)
#pragma unroll
    for (int r = 0; r < 4; ++r) {
      int m = w * 32 + mt * 16 + lg * 4 + r;
      if (r0 + m < N) {
#pragma unroll
        for (int nt = 0; nt < 8; ++nt) {
          int n = nt * 16 + l15;
          a_s[m * LDP + n] = f2bf(x[(r0 + m) * HD + n] + acc2[mt][nt][r] + b2[n]);
        }
      }
    }
  __syncthreads();

  for (int row = w; row < 128; row += 4) {
    if (r0 + row >= N) continue;
    float v1 = bf2f(a_s[row * LDP + lane]), v2 = bf2f(a_s[row * LDP + 64 + lane]);
    float s = v1 + v2, sq = v1 * v1 + v2 * v2;
    for (int o = 32; o > 0; o >>= 1) { s += __shfl_xor(s, o); sq += __shfl_xor(sq, o); }
    float mean = s * (1.f / 128.f);
    float var = sq * (1.f / 128.f) - mean * mean;
    float rs = rsqrtf(var + 1e-5f);
    xo[(r0 + row) * HD + lane]      = (v1 - mean) * rs * g1[lane] + bt1[lane];
    xo[(r0 + row) * HD + 64 + lane] = (v2 - mean) * rs * g1[lane + 64] + bt1[lane + 64];
  }
}

// ======== FUSED chem kernel: qkv -> 4-head attn -> oproj+LN2 -> ffn1 -> ffn2 ======
__global__ __launch_bounds__(256) void chem_kernel(
    float* __restrict__ xo,
    const unsigned short* __restrict__ inwb, const float* __restrict__ in_b,
    const unsigned short* __restrict__ wob, const float* __restrict__ bo,
    const float* __restrict__ g2, const float* __restrict__ bt2,
    const unsigned short* __restrict__ f1wb, const float* __restrict__ f1b,
    const unsigned short* __restrict__ f2wb, const float* __restrict__ f2b,
    const void* __restrict__ chem, const int* __restrict__ flag) {
  __shared__ unsigned short xc_s[128 * LDP];  // xc -> P -> h2
  __shared__ unsigned short q_s[128 * LDP];   // q  -> O -> u[0:128]
  __shared__ unsigned short k_s[128 * LDP];   // k  -> y stash (bf16)
  __shared__ unsigned short vt_s[128 * LDP];  // v^T -> u[128:256]
  __shared__ int s_row[128];
  const int tid = threadIdx.x, chunk = blockIdx.x;
  const int is64 = *flag;
  if (tid < 128) s_row[tid] = idx_at(chem, (long long)chunk * 128 + tid, is64);
  __syncthreads();

  for (int i = tid; i < 2048; i += 256) {
    int r = i >> 4, c = (i & 15) << 3;
    const float* src = &xo[(size_t)s_row[r] * HD + c];
    float4 f0 = *(const float4*)&src[0];
    float4 f1 = *(const float4*)&src[4];
    u16x4 h0 = { f2bf(f0.x), f2bf(f0.y), f2bf(f0.z), f2bf(f0.w) };
    u16x4 h1 = { f2bf(f1.x), f2bf(f1.y), f2bf(f1.z), f2bf(f1.w) };
    *(u16x4*)&xc_s[r * LDP + c] = h0;
    *(u16x4*)&xc_s[r * LDP + c + 4] = h1;
  }
  __syncthreads();

  const int lane = tid & 63, w = tid >> 6;
  const int l15 = lane & 15, lg = lane >> 4;
  const float scale = 0.1767766952966369f;

  for (int sec = 0; sec < 3; ++sec) {
    f32x4 acc[2][8];
#pragma unroll
    for (int mt = 0; mt < 2; ++mt)
#pragma unroll
      for (int nt = 0; nt < 8; ++nt) acc[mt][nt] = (f32x4){0.f, 0.f, 0.f, 0.f};
    mfma_tile_gb(xc_s, inwb + (size_t)sec * 128 * 128, 128, w, l15, lg, acc);
#pragma unroll
    for (int mt = 0; mt < 2; ++mt)
#pragma unroll
      for (int r = 0; r < 4; ++r) {
        int m = w * 32 + mt * 16 + lg * 4 + r;
#pragma unroll
        for (int nt = 0; nt < 8; ++nt) {
          int n = nt * 16 + l15;
          float t = acc[mt][nt][r] + in_b[sec * 128 + n];
          if (sec == 0)      q_s[m * LDP + n] = f2bf(t * scale);
          else if (sec == 1) k_s[m * LDP + n] = f2bf(t);
          else               vt_s[n * LDP + m] = f2bf(t);
        }
      }
  }
  __syncthreads();

  f32x4 oacc[2][8];
#pragma unroll
  for (int mt = 0; mt < 2; ++mt)
#pragma unroll
    for (int nt = 0; nt < 8; ++nt) oacc[mt][nt] = (f32x4){0.f, 0.f, 0.f, 0.f};

  for (int h = 0; h < 4; ++h) {
    f32x4 sacc[2][8];
#pragma unroll
    for (int mt = 0; mt < 2; ++mt)
#pragma unroll
      for (int nt = 0; nt < 8; ++nt) sacc[mt][nt] = (f32x4){0.f, 0.f, 0.f, 0.f};
    {
      bf16x8 a[2], b[8];
#pragma unroll
      for (int mt = 0; mt < 2; ++mt)
        a[mt] = *(const bf16x8*)&q_s[(w * 32 + mt * 16 + l15) * LDP + h * 32 + lg * 8];
#pragma unroll
      for (int nt = 0; nt < 8; ++nt)
        b[nt] = *(const bf16x8*)&k_s[(nt * 16 + l15) * LDP + h * 32 + lg * 8];
#pragma unroll
      for (int mt = 0; mt < 2; ++mt)
#pragma unroll
        for (int nt = 0; nt < 8; ++nt)
          sacc[mt][nt] = __builtin_amdgcn_mfma_f32_16x16x32_bf16(a[mt], b[nt], sacc[mt][nt], 0, 0, 0);
    }
#pragma unroll
    for (int mt = 0; mt < 2; ++mt)
#pragma unroll
      for (int r = 0; r < 4; ++r) {
        int m = w * 32 + mt * 16 + lg * 4 + r;
        float mx = -1e30f;
#pragma unroll
        for (int nt = 0; nt < 8; ++nt) mx = fmaxf(mx, sacc[mt][nt][r]);
        for (int o = 8; o > 0; o >>= 1) mx = fmaxf(mx, __shfl_xor(mx, o));
        float sm = 0.f;
        float p[8];
#pragma unroll
        for (int nt = 0; nt < 8; ++nt) { p[nt] = __expf(sacc[mt][nt][r] - mx); sm += p[nt]; }
        for (int o = 8; o > 0; o >>= 1) sm += __shfl_xor(sm, o);
        float inv = 1.f / sm;
#pragma unroll
        for (int nt = 0; nt < 8; ++nt)
          xc_s[m * LDP + nt * 16 + l15] = f2bf(p[nt] * inv);
      }
#pragma unroll
    for (int kk = 0; kk < 4; ++kk) {
      bf16x8 pa[2], vb[2];
#pragma unroll
      for (int mt = 0; mt < 2; ++mt)
        pa[mt] = *(const bf16x8*)&xc_s[(w * 32 + mt * 16 + l15) * LDP + kk * 32 + lg * 8];
#pragma unroll
      for (int nt2 = 0; nt2 < 2; ++nt2)
        vb[nt2] = *(const bf16x8*)&vt_s[(h * 32 + nt2 * 16 + l15) * LDP + kk * 32 + lg * 8];
#pragma unroll
      for (int mt = 0; mt < 2; ++mt)
#pragma unroll
        for (int nt2 = 0; nt2 < 2; ++nt2)
          oacc[mt][h * 2 + nt2] =
              __builtin_amdgcn_mfma_f32_16x16x32_bf16(pa[mt], vb[nt2], oacc[mt][h * 2 + nt2], 0, 0, 0);
    }
  }
  __syncthreads();

#pragma unroll
  for (int mt = 0; mt < 2; ++mt)
#pragma unroll
    for (int r = 0; r < 4; ++r) {
      int m = w * 32 + mt * 16 + lg * 4 + r;
#pragma unroll
      for (int nt = 0; nt < 8; ++nt)
        q_s[m * LDP + nt * 16 + l15] = f2bf(oacc[mt][nt][r]);
    }

  f32x4 pacc[2][8];
#pragma unroll
  for (int mt = 0; mt < 2; ++mt)
#pragma unroll
    for (int nt = 0; nt < 8; ++nt) pacc[mt][nt] = (f32x4){0.f, 0.f, 0.f, 0.f};
  mfma_tile_gb(q_s, wob, 128, w, l15, lg, pacc);

#pragma unroll
  for (int mt = 0; mt < 2; ++mt)
#pragma unroll
    for (int r = 0; r < 4; ++r) {
      int m = w * 32 + mt * 16 + lg * 4 + r;
      const float* xrow = &xo[(size_t)s_row[m] * HD];
      float y[8];
      float s = 0.f, sq = 0.f;
#pragma unroll
      for (int nt = 0; nt < 8; ++nt) {
        int n = nt * 16 + l15;
        y[nt] = xrow[n] + pacc[mt][nt][r] + bo[n];
        s += y[nt]; sq += y[nt] * y[nt];
      }
      for (int o = 8; o > 0; o >>= 1) { s += __shfl_xor(s, o); sq += __shfl_xor(sq, o); }
      float mean = s * (1.f / 128.f);
      float var = sq * (1.f / 128.f) - mean * mean;
      float rs = rsqrtf(var + 1e-5f);
#pragma unroll
      for (int nt = 0; nt < 8; ++nt) {
        int n = nt * 16 + l15;
        xc_s[m * LDP + n] = f2bf((y[nt] - mean) * rs * g2[n] + bt2[n]);
        k_s[m * LDP + n]  = f2bf(y[nt]);
      }
    }

  for (int sec = 0; sec < 2; ++sec) {
    f32x4 acc[2][8];
#pragma unroll
    for (int mt = 0; mt < 2; ++mt)
#pragma unroll
      for (int nt = 0; nt < 8; ++nt) acc[mt][nt] = (f32x4){0.f, 0.f, 0.f, 0.f};
    mfma_tile_gb(xc_s, f1wb + (size_t)sec * 128 * 128, 128, w, l15, lg, acc);
    unsigned short* ub = (sec == 0) ? q_s : vt_s;
#pragma unroll
    for (int mt = 0; mt < 2; ++mt)
#pragma unroll
      for (int r = 0; r < 4; ++r) {
        int m = w * 32 + mt * 16 + lg * 4 + r;
#pragma unroll
        for (int nt = 0; nt < 8; ++nt) {
          int n = nt * 16 + l15;
          float t = acc[mt][nt][r] + f1b[sec * 128 + n];
          ub[m * LDP + n] = f2bf(t > 0.f ? t : 0.f);
        }
      }
  }

  f32x4 facc[2][8];
#pragma unroll
  for (int mt = 0; mt < 2; ++mt)
#pragma unroll
    for (int nt = 0; nt < 8; ++nt) facc[mt][nt] = (f32x4){0.f, 0.f, 0.f, 0.f};
  mfma_tile_gb(q_s, f2wb, 256, w, l15, lg, facc);
  mfma_tile_gb(vt_s, f2wb + 128, 256, w, l15, lg, facc);

#pragma unroll
  for (int mt = 0; mt < 2; ++mt)
#pragma unroll
    for (int r = 0; r < 4; ++r) {
      int m = w * 32 + mt * 16 + lg * 4 + r;
      float* orow = &xo[(size_t)s_row[m] * HD];
#pragma unroll
      for (int nt = 0; nt < 8; ++nt) {
        int n = nt * 16 + l15;
        orow[n] = bf2f(k_s[m * LDP + n]) + facc[mt][nt][r] + f2b[n];
      }
    }
}

// ================= FALLBACK (small ws): atomic edge + fused node =================
__global__ __launch_bounds__(256) void edge_kernel(
    const float* __restrict__ x, const float* __restrict__ ea,
    const float* __restrict__ We, const float* __restrict__ be,
    const void* __restrict__ ei, const int* __restrict__ flag,
    float* __restrict__ agg, int E, int N) {
  __shared__ unsigned short ea_s[128 * LDP];
  __shared__ unsigned short we_s[128 * LDP];
  __shared__ int s_src[128];
  __shared__ int s_dst[128];
  const int tid = threadIdx.x;
  const long long e0 = (long long)blockIdx.x * 128;
  const int is64 = *flag;
  if (tid < 128) {
    long long e = e0 + tid;
    int s = 0, d = 0;
    if (e < E) { s = idx_at(ei, e, is64); d = idx_at(ei, (long long)E + e, is64); }
    s_src[tid] = s; s_dst[tid] = d;
  }
  for (int i = tid; i < 128 * 32; i += 256) {
    int r = i >> 5, c = (i & 31) << 2;
    float4 f = {0.f, 0.f, 0.f, 0.f};
    if (e0 + r < E) f = *(const float4*)&ea[(e0 + r) * HD + c];
    u16x4 h = { f2bf(f.x), f2bf(f.y), f2bf(f.z), f2bf(f.w) };
    *(u16x4*)&ea_s[r * LDP + c] = h;
    float4 g = *(const float4*)&We[r * HD + c];
    u16x4 hw = { f2bf(g.x), f2bf(g.y), f2bf(g.z), f2bf(g.w) };
    *(u16x4*)&we_s[r * LDP + c] = hw;
  }
  __syncthreads();
  const int lane = tid & 63, w = tid >> 6;
  const int l15 = lane & 15, lg = lane >> 4;
  f32x4 acc[2][8];
#pragma unroll
  for (int mt = 0; mt < 2; ++mt)
#pragma unroll
    for (int nt = 0; nt < 8; ++nt) acc[mt][nt] = (f32x4){0.f, 0.f, 0.f, 0.f};
  mfma_tile_128(ea_s, we_s, w, l15, lg, acc);
  float bev[8];
#pragma unroll
  for (int nt = 0; nt < 8; ++nt) bev[nt] = be[nt * 16 + l15];
#pragma unroll
  for (int mt = 0; mt < 2; ++mt) {
#pragma unroll
    for (int r = 0; r < 4; ++r) {
      int m = w * 32 + mt * 16 + lg * 4 + r;
      if (e0 + m >= E) continue;
      const float* xrow = x + (size_t)s_src[m] * HD;
      float* arow = agg + (size_t)s_dst[m] * HD;
#pragma unroll
      for (int nt = 0; nt < 8; ++nt) {
        int n = nt * 16 + l15;
        float val = acc[mt][nt][r] + bev[nt] + xrow[n];
        if (val > 0.f) unsafeAtomicAdd(&arow[n], val);
      }
    }
  }
}

__global__ __launch_bounds__(256) void node_kernel(
    const float* __restrict__ x, float* xo,
    const float* __restrict__ W1, const float* __restrict__ b1,
    const float* __restrict__ W2, const float* __restrict__ b2,
    const float* __restrict__ g1, const float* __restrict__ bt1, int N) {
  __shared__ char smem[2 * 128 * LDP * 2];
  unsigned short* a_s = (unsigned short*)smem;
  unsigned short* w_s = (unsigned short*)smem + 128 * LDP;
  float* y_s = (float*)smem;
  const int tid = threadIdx.x;
  const long long r0 = (long long)blockIdx.x * 128;
  for (int i = tid; i < 128 * 32; i += 256) {
    int r = i >> 5, c = (i & 31) << 2;
    float4 f = {0.f, 0.f, 0.f, 0.f};
    if (r0 + r < N) {
      float4 xa = *(const float4*)&x[(r0 + r) * HD + c];
      float4 ag = *(const float4*)&xo[(r0 + r) * HD + c];
      f.x = xa.x + ag.x; f.y = xa.y + ag.y; f.z = xa.z + ag.z; f.w = xa.w + ag.w;
    }
    u16x4 h = { f2bf(f.x), f2bf(f.y), f2bf(f.z), f2bf(f.w) };
    *(u16x4*)&a_s[r * LDP + c] = h;
    float4 g = *(const float4*)&W1[r * HD + c];
    u16x4 hw = { f2bf(g.x), f2bf(g.y), f2bf(g.z), f2bf(g.w) };
    *(u16x4*)&w_s[r * LDP + c] = hw;
  }
  __syncthreads();
  const int lane = tid & 63, w = tid >> 6;
  const int l15 = lane & 15, lg = lane >> 4;
  f32x4 acc[2][8];
#pragma unroll
  for (int mt = 0; mt < 2; ++mt)
#pragma unroll
    for (int nt = 0; nt < 8; ++nt) acc[mt][nt] = (f32x4){0.f, 0.f, 0.f, 0.f};
  mfma_tile_128(a_s, w_s, w, l15, lg, acc);
  __syncthreads();
#pragma unroll
  for (int mt = 0; mt < 2; ++mt)
#pragma unroll
    for (int r = 0; r < 4; ++r) {
      int m = w * 32 + mt * 16 + lg * 4 + r;
#pragma unroll
      for (int nt = 0; nt < 8; ++nt) {
        int n = nt * 16 + l15;
        float t = acc[mt][nt][r] + b1[n];
        a_s[m * LDP + n] = f2bf(t > 0.f ? t : 0.f);
      }
    }
  stage_f32s(w_s, W2, HD, tid, 256);
  __syncthreads();
  f32x4 acc2[2][8];
#pragma unroll
  for (int mt = 0; mt < 2; ++mt)
#pragma unroll
    for (int nt = 0; nt < 8; ++nt) acc2[mt][nt] = (f32x4){0.f, 0.f, 0.f, 0.f};
  mfma_tile_128(a_s, w_s, w, l15, lg, acc2);
  __syncthreads();
#pragma unroll
  for (int mt = 0; mt < 2; ++mt)
#pragma unroll
    for (int r = 0; r < 4; ++r) {
      int m = w * 32 + mt * 16 + lg * 4 + r;
      if (r0 + m < N) {
#pragma unroll
        for (int nt = 0; nt < 8; ++nt) {
          int n = nt * 16 + l15;
          y_s[m * 132 + n] = x[(r0 + m) * HD + n] + acc2[mt][nt][r] + b2[n];
        }
      }
    }
  __syncthreads();
  for (int row = w; row < 128; row += 4) {
    if (r0 + row >= N) continue;
    float v1 = y_s[row * 132 + lane], v2 = y_s[row * 132 + 64 + lane];
    float s = v1 + v2, sq = v1 * v1 + v2 * v2;
    for (int o = 32; o > 0; o >>= 1) { s += __shfl_xor(s, o); sq += __shfl_xor(sq, o); }
    float mean = s * (1.f / 128.f);
    float var = sq * (1.f / 128.f) - mean * mean;
    float rs = rsqrtf(var + 1e-5f);
    xo[(r0 + row) * HD + lane]      = (v1 - mean) * rs * g1[lane] + bt1[lane];
    xo[(r0 + row) * HD + 64 + lane] = (v2 - mean) * rs * g1[lane + 64] + bt1[lane + 64];
  }
}

extern "C" void kernel_launch(void* const* d_in, const int* in_sizes, int n_in,
                              void* d_out, int out_size, void* d_ws, size_t ws_size,
                              hipStream_t stream) {
  const float* x    = (const float*)d_in[0];
  const float* ea   = (const float*)d_in[1];
  const float* We   = (const float*)d_in[2];
  const float* be   = (const float*)d_in[3];
  const float* W1   = (const float*)d_in[4];
  const float* b1   = (const float*)d_in[5];
  const float* W2   = (const float*)d_in[6];
  const float* b2   = (const float*)d_in[7];
  const float* g1   = (const float*)d_in[8];
  const float* bt1  = (const float*)d_in[9];
  const float* in_w = (const float*)d_in[10];
  const float* in_b = (const float*)d_in[11];
  const float* outw = (const float*)d_in[12];
  const float* outb = (const float*)d_in[13];
  const float* g2   = (const float*)d_in[14];
  const float* bt2  = (const float*)d_in[15];
  const float* f1w  = (const float*)d_in[16];
  const float* f1b  = (const float*)d_in[17];
  const float* f2w  = (const float*)d_in[18];
  const float* f2b  = (const float*)d_in[19];
  const void*  ei   = d_in[20];
  const void*  chem = d_in[21];
  const int N  = in_sizes[0] / HD;
  const int E  = in_sizes[1] / HD;
  const int NC = in_sizes[21];
  const int NB = (N + SCH - 1) / SCH;
  float* xo = (float*)d_out;

  char* ws = (char*)d_ws;
  size_t o = 0;
  auto alloc = [&](size_t bytes) { size_t p = o; o = (o + bytes + 255) & ~255ULL; return p; };
  size_t o_flag = alloc(4);
  size_t o_webf = alloc(128 * 128 * 2);
  size_t o_w1b  = alloc(128 * 128 * 2);
  size_t o_w2b  = alloc(128 * 128 * 2);
  size_t o_inwb = alloc(384 * 128 * 2);
  size_t o_wob  = alloc(128 * 128 * 2);
  size_t o_f1wb = alloc(256 * 128 * 2);
  size_t o_f2wb = alloc(128 * 256 * 2);
  size_t o_xbf  = alloc((size_t)N * 128 * 2);
  size_t o_hbf  = alloc((size_t)N * 128 * 2);
  size_t o_deg  = alloc((size_t)N * 4);
  size_t o_off  = alloc((size_t)(N + 1) * 4);
  size_t o_cur  = alloc((size_t)N * 4);
  size_t o_bsum = alloc((size_t)NB * 4);
  size_t o_msg  = alloc((size_t)E * 128 * 2);
  size_t need = o;

  int*            flag = (int*)(ws + o_flag);
  unsigned short* webf = (unsigned short*)(ws + o_webf);
  unsigned short* w1b  = (unsigned short*)(ws + o_w1b);
  unsigned short* w2b  = (unsigned short*)(ws + o_w2b);
  unsigned short* inwb = (unsigned short*)(ws + o_inwb);
  unsigned short* wob  = (unsigned short*)(ws + o_wob);
  unsigned short* f1wb = (unsigned short*)(ws + o_f1wb);
  unsigned short* f2wb = (unsigned short*)(ws + o_f2wb);
  unsigned short* xbf  = (unsigned short*)(ws + o_xbf);
  unsigned short* hbf  = (unsigned short*)(ws + o_hbf);
  int*            deg  = (int*)(ws + o_deg);
  int*            off  = (int*)(ws + o_off);
  int*            cur  = (int*)(ws + o_cur);
  int*            bsum = (int*)(ws + o_bsum);
  unsigned short* msg  = (unsigned short*)(ws + o_msg);

  detect_idx_kernel<<<1, 64, 0, stream>>>(ei, E, N, flag);
  conv_weights_kernel<<<dim3(640), 256, 0, stream>>>(W1, W2, in_w, outw, f1w, f2w,
                                                     w1b, w2b, inwb, wob, f1wb, f2wb);

  if (ws_size >= need) {
    hipMemsetAsync(deg, 0, (size_t)N * 4, stream);
    conv_x_kernel<<<dim3((N * 16 + 255) / 256), 256, 0, stream>>>(x, xbf, (long long)N * 16);
    hist_kernel<<<dim3(1024), 256, 0, stream>>>(ei, flag, deg, E);
    scan_a<<<dim3(NB), 256, 0, stream>>>(deg, bsum, N);
    if (NB <= 128) scan_b2<<<1, 128, 0, stream>>>(bsum, off, NB, N);
    else           scan_b<<<1, 64, 0, stream>>>(bsum, off, NB, N);
    scan_c<<<dim3(NB), 256, 0, stream>>>(deg, bsum, off, cur, N);
    conv_we_kernel<<<dim3(64), 256, 0, stream>>>(We, webf);
    edge_kernel11<<<dim3((E + 127) / 128), 256, 0, stream>>>(xbf, ea, webf, be, ei,
                                                             flag, cur, msg, E);
    gather_kernel<<<dim3((N + 15) / 16), 256, 0, stream>>>(xbf, off, msg, hbf, N);
    mlp_kernel<<<dim3((N + 127) / 128), 256, 0, stream>>>(x, xo, hbf, w1b, b1, w2b,
                                                          b2, g1, bt1, N);
  } else {
    hipMemsetAsync(xo, 0, (size_t)N * HD * sizeof(float), stream);
    edge_kernel<<<dim3((E + 127) / 128), 256, 0, stream>>>(x, ea, We, be, ei, flag, xo, E, N);
    node_kernel<<<dim3((N + 127) / 128), 256, 0, stream>>>(x, xo, W1, b1, W2, b2, g1, bt1, N);
  }

  chem_kernel<<<dim3(NC / 128), 256, 0, stream>>>(xo, inwb, in_b, wob, outb, g2, bt2,
                                                  f1wb, f1b, f2wb, f2b, chem, flag);
}